// Round 7
// baseline (594.240 us; speedup 1.0000x reference)
//
#include <hip/hip_runtime.h>

typedef unsigned short u16;
typedef unsigned int   u32;
typedef __attribute__((ext_vector_type(8))) short bf16x8;   // 8 bf16 (4 VGPRs)
typedef __attribute__((ext_vector_type(4))) float f32x4;    // mfma acc

#define EPS 1e-5f
#define MFMA(a,b,c) __builtin_amdgcn_mfma_f32_16x16x32_bf16(a,b,c,0,0,0)

// ---- wbuf (fp32) element offsets ----
constexpr int OB_b1=0, OB_g1=64, OB_be1=128, OB_b2=192, OB_bm1=256, OB_w192=320,
              OB_bm2=384, OB_gn=448, OB_bn=512, OB_bg1=576, OB_bg2=640,
              OB_Wg1=704, OB_Wg2=8896, WB_TOT=12992;
// ---- frag buffer (u16/bf16) element offsets ----
constexpr int FR_Wm1=0;          // 24 frags (K=192) = 12288
constexpr int FR_Wm2=12288;      // 8 frags  (K=64)  = 4096
constexpr int FR_rel=16384;      // 7 rows x 80 (pad) = 560, alloc 576
constexpr int FR_W1 =16960;      // 32 frags (K=256) = 16384
constexpr int FR_W2 =33344;      // 8 frags  (K=64)  = 4096
constexpr int FR_TOT=37440;

__device__ __forceinline__ float bf2f(u32 u) { return __uint_as_float(u << 16); }
__device__ __forceinline__ u16 f2bf(float f) {
  u32 b = __float_as_uint(f);
  return (u16)((b + 0x7fffu + ((b >> 16) & 1u)) >> 16);  // RNE
}
__device__ __forceinline__ u32 fkey(float f) {  // monotone float->u32 (finite)
  u32 b = __float_as_uint(f);
  return (b & 0x80000000u) ? ~b : (b | 0x80000000u);
}

// coalesced global->LDS direct copy, 16B/lane (dest = base + lane*16)
__device__ __forceinline__ void gld_lds16(const void* g, void* l) {
  __builtin_amdgcn_global_load_lds(
      (const __attribute__((address_space(1))) void*)g,
      (__attribute__((address_space(3))) void*)l, 16, 0, 0);
}

// ---- prep (+hist fused): wbuf, frag swizzles, dst histogram, zeros ----
__launch_bounds__(256)
__global__ void k_prep(const float* __restrict__ W1, const float* __restrict__ b1,
                       const float* __restrict__ g1, const float* __restrict__ be1,
                       const float* __restrict__ W2, const float* __restrict__ b2,
                       const float* __restrict__ rel_emb,
                       const float* __restrict__ Wm1, const float* __restrict__ bm1,
                       const float* __restrict__ Wm2, const float* __restrict__ bm2,
                       const float* __restrict__ gn, const float* __restrict__ bn,
                       const float* __restrict__ Wg1, const float* __restrict__ bg1,
                       const float* __restrict__ Wg2, const float* __restrict__ bg2,
                       float* __restrict__ wbuf, u16* __restrict__ frags,
                       const float* __restrict__ te, int* __restrict__ cnt,
                       float* __restrict__ gsum, u32* __restrict__ gmax,
                       int* __restrict__ ticket, int E, int N) {
  int tid = blockIdx.x * 256 + threadIdx.x;
  int nth = gridDim.x * 256;
  if (tid == 0) *ticket = 0;
  for (int i = tid; i < 64; i += nth) {
    wbuf[OB_b1 + i] = b1[i];   wbuf[OB_g1 + i] = g1[i];
    wbuf[OB_be1 + i] = be1[i]; wbuf[OB_b2 + i] = b2[i];
    wbuf[OB_bm1 + i] = bm1[i]; wbuf[OB_w192 + i] = Wm1[192 * 64 + i];
    wbuf[OB_bm2 + i] = bm2[i]; wbuf[OB_gn + i] = gn[i];
    wbuf[OB_bn + i] = bn[i];   wbuf[OB_bg1 + i] = bg1[i];
    wbuf[OB_bg2 + i] = bg2[i];
    gsum[i] = 0.f; gmax[i] = 0u;
  }
  for (int i = tid; i < 8192; i += nth) wbuf[OB_Wg1 + i] = Wg1[i];
  for (int i = tid; i < 4096; i += nth) wbuf[OB_Wg2 + i] = Wg2[i];
  for (int idx = tid; idx < 16384; idx += nth) {
    int f = idx >> 9, L = (idx >> 3) & 63, j = idx & 7;
    int k = (f >> 2) * 32 + ((L >> 4) << 3) + j, n = ((f & 3) << 4) + (L & 15);
    frags[FR_W1 + idx] = f2bf(W1[k * 64 + n]);
  }
  for (int idx = tid; idx < 4096; idx += nth) {
    int f = idx >> 9, L = (idx >> 3) & 63, j = idx & 7;
    int k = (f >> 2) * 32 + ((L >> 4) << 3) + j, n = ((f & 3) << 4) + (L & 15);
    frags[FR_W2 + idx] = f2bf(W2[k * 64 + n]);
  }
  for (int idx = tid; idx < 12288; idx += nth) {
    int f = idx >> 9, L = (idx >> 3) & 63, j = idx & 7;
    int k = (f >> 2) * 32 + ((L >> 4) << 3) + j, n = ((f & 3) << 4) + (L & 15);
    frags[FR_Wm1 + idx] = f2bf(Wm1[k * 64 + n]);
  }
  for (int idx = tid; idx < 4096; idx += nth) {
    int f = idx >> 9, L = (idx >> 3) & 63, j = idx & 7;
    int k = (f >> 2) * 32 + ((L >> 4) << 3) + j, n = ((f & 3) << 4) + (L & 15);
    frags[FR_Wm2 + idx] = f2bf(Wm2[k * 64 + n]);
  }
  for (int idx = tid; idx < 576; idx += nth) {
    int r = idx / 80, c = idx % 80;
    frags[FR_rel + idx] = (r < 7 && c < 64) ? f2bf(rel_emb[r * 64 + c]) : (u16)0;
  }
  // fused dst histogram
  for (int e = tid; e < E; e += nth) {
    float4 v = *(const float4*)(te + (size_t)e * 4);
    int d = min(max((int)v.y, 0), N - 1);
    atomicAdd(&cnt[d], 1);
  }
}

// ---- single-block exclusive scan: cur(counts) -> cur(cursors) ----
__launch_bounds__(1024)
__global__ void k_scan(int* __restrict__ cur, int N) {
  __shared__ int sd[1024];
  int t = threadIdx.x;
  int K = (N + 1023) / 1024;
  int beg = t * K, end = min(beg + K, N);
  int loc = 0;
  for (int i = beg; i < end; i++) loc += cur[i];
  sd[t] = loc; __syncthreads();
  for (int s = 1; s < 1024; s <<= 1) {
    int o = (t >= s) ? sd[t - s] : 0;
    __syncthreads();
    sd[t] += o;
    __syncthreads();
  }
  int run = sd[t] - loc;   // exclusive prefix of this chunk
  for (int i = beg; i < end; i++) {
    int c = cur[i];
    cur[i] = run;
    run += c;
  }
}

__launch_bounds__(256)
__global__ void k_place(const float* __restrict__ te, int* __restrict__ cur,
                        uint4* __restrict__ sorted, int E, int N) {
  int i = blockIdx.x * 256 + threadIdx.x, st = gridDim.x * 256;
  for (int e = i; e < E; e += st) {
    float4 v = *(const float4*)(te + (size_t)e * 4);
    int s = min(max((int)v.x, 0), N - 1);
    int d = min(max((int)v.y, 0), N - 1);
    int r = min(max((int)v.z, 0), 6);
    int pos = atomicAdd(&cur[d], 1);
    uint4 rec; rec.x = (u32)s; rec.y = (u32)d; rec.z = (u32)r; rec.w = __float_as_uint(v.w);
    sorted[pos] = rec;
  }
}

// ---- stage A (MFMA): h = relu(relu(LN(X@W1+b1)) @ W2 + b2) ----
__launch_bounds__(256, 4)
__global__ void k_h(const float* __restrict__ X, const float* __restrict__ wbuf,
                    const u16* __restrict__ frags, u16* __restrict__ hb,
                    float* __restrict__ agg, int N) {
  __shared__ __align__(16) float xb[2][16 * 256];   // 2 x 16 KB X tile
  __shared__ __align__(16) u16 st[16 * 72];         // bf16 h1 tile (pad 72)
  __shared__ float sred[2][16][4];                  // row {sum,sumsq} per wave

  int lane = threadIdx.x & 63, wave = threadIdx.x >> 6;
  int m = lane & 15, quad = lane >> 4;
  int col = wave * 16 + m;

  bf16x8 bw1[8], bw2[2];
  #pragma unroll
  for (int ks = 0; ks < 8; ks++)
    bw1[ks] = *(const bf16x8*)(frags + FR_W1 + ((ks * 4 + wave) * 64 + lane) * 8);
  #pragma unroll
  for (int ks = 0; ks < 2; ks++)
    bw2[ks] = *(const bf16x8*)(frags + FR_W2 + ((ks * 4 + wave) * 64 + lane) * 8);

  float b1v = wbuf[OB_b1 + col], g1v = wbuf[OB_g1 + col];
  float be1v = wbuf[OB_be1 + col], b2v = wbuf[OB_b2 + col];

  int ntiles = (N + 15) / 16;
  int xorm = (m & 7) << 4;

  auto stage = [&](int t, int buf) {
    int n0s = t * 16;
    #pragma unroll
    for (int i = 0; i < 4; i++) {
      int r = wave * 4 + i;
      int nr = min(n0s + r, N - 1);
      const char* src = (const char*)(X + (size_t)nr * 256);
      int soff = (lane * 16) ^ ((r & 7) << 4);
      gld_lds16(src + soff, (char*)&xb[buf][0] + r * 1024);
    }
  };

  int cur = 0;
  if (blockIdx.x < ntiles) stage(blockIdx.x, 0);

  for (int t = blockIdx.x; t < ntiles; t += gridDim.x) {
    __syncthreads();
    if (t + (int)gridDim.x < ntiles) stage(t + gridDim.x, cur ^ 1);

    int n0 = t * 16;
    const char* xp = (const char*)&xb[cur][0];

    f32x4 acc = {};
    #pragma unroll
    for (int ks = 0; ks < 8; ks++) {
      int base = m * 1024 + ks * 128 + quad * 32;
      float4 u0 = *(const float4*)(xp + (base ^ xorm));
      float4 u1 = *(const float4*)(xp + ((base + 16) ^ xorm));
      bf16x8 a;
      a[0] = (short)f2bf(u0.x); a[1] = (short)f2bf(u0.y);
      a[2] = (short)f2bf(u0.z); a[3] = (short)f2bf(u0.w);
      a[4] = (short)f2bf(u1.x); a[5] = (short)f2bf(u1.y);
      a[6] = (short)f2bf(u1.z); a[7] = (short)f2bf(u1.w);
      acc = MFMA(a, bw1[ks], acc);
    }

    float vv[4];
    #pragma unroll
    for (int r = 0; r < 4; r++) vv[r] = acc[r] + b1v;
    #pragma unroll
    for (int r = 0; r < 4; r++) {
      float s = vv[r], q = vv[r] * vv[r];
      #pragma unroll
      for (int mk = 8; mk >= 1; mk >>= 1) {
        s += __shfl_xor(s, mk, 64);
        q += __shfl_xor(q, mk, 64);
      }
      if (m == 0) { sred[0][quad * 4 + r][wave] = s; sred[1][quad * 4 + r][wave] = q; }
    }
    __syncthreads();
    #pragma unroll
    for (int r = 0; r < 4; r++) {
      int row = quad * 4 + r;
      float4 S = *(const float4*)&sred[0][row][0];
      float4 Q = *(const float4*)&sred[1][row][0];
      float mu = (S.x + S.y + S.z + S.w) * (1.f / 64.f);
      float vq = (Q.x + Q.y + Q.z + Q.w) * (1.f / 64.f) - mu * mu;
      float rs = rsqrtf(fmaxf(vq, 0.f) + EPS);
      float h1 = fmaxf(fmaf((vv[r] - mu) * rs, g1v, be1v), 0.f);
      st[row * 72 + col] = f2bf(h1);
    }
    __syncthreads();

    f32x4 acc2 = {};
    #pragma unroll
    for (int ks = 0; ks < 2; ks++) {
      bf16x8 a2 = *(const bf16x8*)(st + m * 72 + ks * 32 + quad * 8);
      acc2 = MFMA(a2, bw2[ks], acc2);
    }
    #pragma unroll
    for (int r = 0; r < 4; r++) {
      int row = n0 + quad * 4 + r;
      if (row < N) {
        float hv = fmaxf(acc2[r] + b2v, 0.f);
        hb[(size_t)row * 64 + col] = f2bf(hv);
        agg[(size_t)row * 64 + col] = hv;
      }
    }
    cur ^= 1;
  }
}

// ---- stage B+C (MFMA): pipelined edge MLP + shfl-transposed run-reduction ----
// LDS 51 KB -> 3 blocks/CU (24 waves). Next tile's sorted-rec loads before
// MFMA1; its hb gathers issue right after MFMA1 (af regs dead) so gather
// latency hides under epilogue+MFMA2+reduce. Messages transposed via shfl
// (no f32 LDS tile, no extra barriers).
__launch_bounds__(512, 5)
__global__ void k_edge(const uint4* __restrict__ sorted, const u16* __restrict__ hb,
                       const float* __restrict__ wbuf, const u16* __restrict__ frags,
                       float* __restrict__ agg, int E, int N) {
  __shared__ __align__(16) u16 sWm1[24 * 512];
  __shared__ __align__(16) u16 sWm2[8 * 512];
  __shared__ __align__(16) u16 srel[576];
  __shared__ __align__(16) u16 stt[8][16 * 72];   // per-wave bf16 t tile

  {
    const uint4* s1 = (const uint4*)(frags + FR_Wm1);
    uint4* d1 = (uint4*)sWm1;
    for (int i = threadIdx.x; i < 1536; i += 512) d1[i] = s1[i];
    const uint4* s2 = (const uint4*)(frags + FR_Wm2);
    uint4* d2 = (uint4*)sWm2;
    for (int i = threadIdx.x; i < 512; i += 512) d2[i] = s2[i];
    const uint4* s3 = (const uint4*)(frags + FR_rel);
    uint4* d3 = (uint4*)srel;
    for (int i = threadIdx.x; i < 72; i += 512) d3[i] = s3[i];
  }
  __syncthreads();

  int lane = threadIdx.x & 63, wave = threadIdx.x >> 6;
  int m = lane & 15, quad = lane >> 4, koff = quad * 8, col0 = m;
  int nthi = lane >> 4;
  u16* stw = stt[wave];

  float bm1v[4], w192v[4], bm2v[4];
  #pragma unroll
  for (int nt = 0; nt < 4; nt++) {
    int c = nt * 16 + col0;
    bm1v[nt] = wbuf[OB_bm1 + c];
    w192v[nt] = wbuf[OB_w192 + c];
    bm2v[nt] = wbuf[OB_bm2 + c];
  }

  int ntiles = (E + 15) >> 4;
  int gw = blockIdx.x * 8 + wave, nwv = gridDim.x * 8;
  int per = (ntiles + nwv - 1) / nwv;
  int tile = gw * per, tend = min(tile + per, ntiles);

  int cd = -1; float cv = 0.f;  // per-lane run carry (lane owns column `lane`)
  int dstv = -1; float wv = 0.f;
  bf16x8 af[6];

  if (tile < tend) {  // prologue: rec + gathers for first tile
    int srcv = 0, relv = 0;
    if (lane < 16) {
      int e = tile * 16 + lane;
      uint4 rc = sorted[min(e, E - 1)];
      srcv = (int)rc.x; dstv = (e < E) ? (int)rc.y : -1;
      relv = (int)rc.z; wv = __uint_as_float(rc.w);
    }
    int sm = __shfl(srcv, m, 64), dmv = __shfl(dstv, m, 64), rm = __shfl(relv, m, 64);
    int dmg = dmv < 0 ? 0 : dmv;
    const u16* hs = hb + (size_t)sm * 64;
    const u16* hd = hb + (size_t)dmg * 64;
    af[0] = *(const bf16x8*)(hs + koff);
    af[1] = *(const bf16x8*)(hs + 32 + koff);
    af[2] = *(const bf16x8*)(hd + koff);
    af[3] = *(const bf16x8*)(hd + 32 + koff);
    af[4] = *(const bf16x8*)(srel + rm * 80 + koff);
    af[5] = *(const bf16x8*)(srel + rm * 80 + 32 + koff);
  }

  for (; tile < tend; tile++) {
    bool hasnext = (tile + 1) < tend;

    // prefetch next sorted rec (full MFMA1 to cover its latency)
    int srcn = 0, dstn = -1, reln = 0; float wn = 0.f;
    if (hasnext && lane < 16) {
      int e = (tile + 1) * 16 + lane;
      uint4 rc = sorted[min(e, E - 1)];
      srcn = (int)rc.x; dstn = (e < E) ? (int)rc.y : -1;
      reln = (int)rc.z; wn = __uint_as_float(rc.w);
    }

    // ---- MFMA1 on current tile ----
    f32x4 acc[4] = {};
    #pragma unroll
    for (int ks = 0; ks < 6; ks++)
      #pragma unroll
      for (int nt = 0; nt < 4; nt++) {
        bf16x8 b = *(const bf16x8*)(sWm1 + (ks * 4 + nt) * 512 + lane * 8);
        acc[nt] = MFMA(af[ks], b, acc[nt]);
      }

    // ---- issue next tile's gathers (af regs free now) ----
    if (hasnext) {
      int sm = __shfl(srcn, m, 64), dmv = __shfl(dstn, m, 64), rm = __shfl(reln, m, 64);
      int dmg = dmv < 0 ? 0 : dmv;
      const u16* hs = hb + (size_t)sm * 64;
      const u16* hd = hb + (size_t)dmg * 64;
      af[0] = *(const bf16x8*)(hs + koff);
      af[1] = *(const bf16x8*)(hs + 32 + koff);
      af[2] = *(const bf16x8*)(hd + koff);
      af[3] = *(const bf16x8*)(hd + 32 + koff);
      af[4] = *(const bf16x8*)(srel + rm * 80 + koff);
      af[5] = *(const bf16x8*)(srel + rm * 80 + 32 + koff);
    }

    // ---- epilogue 1: + bm1 + w*Wm1[192], relu -> bf16 LDS t tile ----
    float wrow[4];
    #pragma unroll
    for (int r = 0; r < 4; r++) wrow[r] = __shfl(wv, quad * 4 + r, 64);
    #pragma unroll
    for (int nt = 0; nt < 4; nt++)
      #pragma unroll
      for (int r = 0; r < 4; r++) {
        float v = fmaf(wrow[r], w192v[nt], acc[nt][r] + bm1v[nt]);
        stw[(quad * 4 + r) * 72 + nt * 16 + col0] = f2bf(fmaxf(v, 0.f));
      }
    __builtin_amdgcn_wave_barrier();

    f32x4 acc2[4] = {};
    #pragma unroll
    for (int ks = 0; ks < 2; ks++) {
      bf16x8 a2 = *(const bf16x8*)(stw + m * 72 + ks * 32 + koff);
      #pragma unroll
      for (int nt = 0; nt < 4; nt++) {
        bf16x8 b = *(const bf16x8*)(sWm2 + (ks * 4 + nt) * 512 + lane * 8);
        acc2[nt] = MFMA(a2, b, acc2[nt]);
      }
    }
    __builtin_amdgcn_wave_barrier();

    // ---- run-reduce: shfl-transpose messages; lane owns column `lane` ----
    // element (row,col) lives in lane (row>>2)*16 + (col&15), acc2[col>>4][row&3]
    #pragma unroll
    for (int r = 0; r < 16; r++) {
      int d = __shfl(dstv, r, 64);
      int sl = ((r >> 2) << 4) + m;
      float c0 = __shfl(acc2[0][r & 3] + bm2v[0], sl, 64);
      float c1 = __shfl(acc2[1][r & 3] + bm2v[1], sl, 64);
      float c2 = __shfl(acc2[2][r & 3] + bm2v[2], sl, 64);
      float c3 = __shfl(acc2[3][r & 3] + bm2v[3], sl, 64);
      float v = nthi == 0 ? c0 : nthi == 1 ? c1 : nthi == 2 ? c2 : c3;
      if (d != cd) {
        if (cd >= 0) atomicAdd(agg + (size_t)cd * 64 + lane, cv);
        cd = d; cv = 0.f;
      }
      if (d >= 0) cv += v;
    }

    dstv = dstn; wv = wn;
  }
  if (cd >= 0) atomicAdd(agg + (size_t)cd * 64 + lane, cv);
}

// ---- stage D1+D2 fused: LN(agg) column sum/max; last block runs final MLP ----
__launch_bounds__(256)
__global__ void k_nodes(const float* __restrict__ agg, const float* __restrict__ wbuf,
                        float* __restrict__ gsum, u32* __restrict__ gmax,
                        int* __restrict__ ticket, float* __restrict__ out, int N) {
  int lane = threadIdx.x & 63, wave = threadIdx.x >> 6;
  int r4 = lane >> 4, c4 = (lane & 15) * 4;
  float4 gnv = *(const float4*)(wbuf + OB_gn + c4);
  float4 bnv = *(const float4*)(wbuf + OB_bn + c4);
  int wid = blockIdx.x * 4 + wave, nw = gridDim.x * 4;
  float sj[4] = {0.f, 0.f, 0.f, 0.f};
  float mj[4] = {-3.0e38f, -3.0e38f, -3.0e38f, -3.0e38f};
  for (int base = wid * 4; base < N; base += nw * 4) {
    int row = base + r4;
    bool ok = row < N;
    float4 av = ok ? *(const float4*)(agg + (size_t)row * 64 + c4)
                   : make_float4(0.f, 0.f, 0.f, 0.f);
    float s = av.x + av.y + av.z + av.w;
    #pragma unroll
    for (int mk = 8; mk >= 1; mk >>= 1) s += __shfl_xor(s, mk, 64);
    float mu = s * (1.f / 64.f);
    float d0 = av.x - mu, d1 = av.y - mu, d2 = av.z - mu, d3 = av.w - mu;
    float q = d0 * d0 + d1 * d1 + d2 * d2 + d3 * d3;
    #pragma unroll
    for (int mk = 8; mk >= 1; mk >>= 1) q += __shfl_xor(q, mk, 64);
    float rs = rsqrtf(q * (1.f / 64.f) + EPS);
    if (ok) {
      float t0 = fmaf(d0 * rs, gnv.x, bnv.x);
      float t1 = fmaf(d1 * rs, gnv.y, bnv.y);
      float t2 = fmaf(d2 * rs, gnv.z, bnv.z);
      float t3 = fmaf(d3 * rs, gnv.w, bnv.w);
      sj[0] += t0; mj[0] = fmaxf(mj[0], t0);
      sj[1] += t1; mj[1] = fmaxf(mj[1], t1);
      sj[2] += t2; mj[2] = fmaxf(mj[2], t2);
      sj[3] += t3; mj[3] = fmaxf(mj[3], t3);
    }
  }
  #pragma unroll
  for (int j = 0; j < 4; j++) {
    sj[j] += __shfl_xor(sj[j], 16, 64);
    sj[j] += __shfl_xor(sj[j], 32, 64);
    mj[j] = fmaxf(mj[j], __shfl_xor(mj[j], 16, 64));
    mj[j] = fmaxf(mj[j], __shfl_xor(mj[j], 32, 64));
  }
  __shared__ float bs[4][64], bm[4][64];
  if (lane < 16) {
    #pragma unroll
    for (int j = 0; j < 4; j++) { bs[wave][c4 + j] = sj[j]; bm[wave][c4 + j] = mj[j]; }
  }
  __syncthreads();
  if (threadIdx.x < 64) {
    int c = threadIdx.x;
    float ts = bs[0][c] + bs[1][c] + bs[2][c] + bs[3][c];
    float tm = fmaxf(fmaxf(bm[0][c], bm[1][c]), fmaxf(bm[2][c], bm[3][c]));
    atomicAdd(gsum + c, ts);
    atomicMax(gmax + c, fkey(tm));
  }
  __syncthreads();   // drains the atomics (compiler emits vmcnt(0) before barrier)

  __shared__ int slast;
  if (threadIdx.x == 0) {
    __threadfence();
    slast = atomicAdd(ticket, 1);
  }
  __syncthreads();
  if (slast == (int)gridDim.x - 1) {   // last block: final 2-layer MLP
    __threadfence();
    __shared__ float g[128];
    __shared__ float y1[64];
    int t = threadIdx.x;
    if (t < 64) {
      g[t] = atomicAdd(gsum + t, 0.f) / (float)N;   // atomic read (coherent)
    } else if (t < 128) {
      u32 k = atomicOr(gmax + (t - 64), 0u);
      u32 b = (k & 0x80000000u) ? (k & 0x7fffffffu) : ~k;
      g[t] = __uint_as_float(b);
    }
    __syncthreads();
    if (t < 64) {
      float a = wbuf[OB_bg1 + t];
      for (int i = 0; i < 128; i++) a = fmaf(g[i], wbuf[OB_Wg1 + i * 64 + t], a);
      y1[t] = fmaxf(a, 0.f);
    }
    __syncthreads();
    if (t < 64) {
      float a = wbuf[OB_bg2 + t];
      for (int k = 0; k < 64; k++) a = fmaf(y1[k], wbuf[OB_Wg2 + k * 64 + t], a);
      out[t] = a;
    }
  }
}

extern "C" void kernel_launch(void* const* d_in, const int* in_sizes, int n_in,
                              void* d_out, int out_size, void* d_ws, size_t ws_size,
                              hipStream_t stream) {
  const int N = in_sizes[0] / 256;
  const int E = in_sizes[1] / 4;

  char* ws = (char*)d_ws;
  size_t p = 0;
  auto rup = [](size_t x) { return (x + 255) & ~(size_t)255; };
  uint4* sorted = (uint4*)(ws + p); p += rup((size_t)E * 16);
  float* agg    = (float*)(ws + p); p += rup((size_t)N * 64 * 4);
  u16*   hb     = (u16*)(ws + p);   p += rup((size_t)N * 128);
  int*   cur    = (int*)(ws + p);   p += rup((size_t)N * 4);
  float* gsum   = (float*)(ws + p); p += 256;
  u32*   gmax   = (u32*)(ws + p);   p += 256;
  int*   ticket = (int*)(ws + p);   p += 256;
  float* wbuf   = (float*)(ws + p); p += rup((size_t)WB_TOT * 4);
  u16*   frags  = (u16*)(ws + p);   p += rup((size_t)FR_TOT * 2);

  const float* X  = (const float*)d_in[0];
  const float* te = (const float*)d_in[1];

  hipMemsetAsync(cur, 0, (size_t)N * 4, stream);
  hipLaunchKernelGGL(k_prep, dim3(1024), dim3(256), 0, stream,
                     (const float*)d_in[2], (const float*)d_in[3], (const float*)d_in[4],
                     (const float*)d_in[5], (const float*)d_in[6], (const float*)d_in[7],
                     (const float*)d_in[8], (const float*)d_in[9], (const float*)d_in[10],
                     (const float*)d_in[11], (const float*)d_in[12], (const float*)d_in[13],
                     (const float*)d_in[14], (const float*)d_in[15], (const float*)d_in[16],
                     (const float*)d_in[17], (const float*)d_in[18], wbuf, frags,
                     te, cur, gsum, gmax, ticket, E, N);

  hipLaunchKernelGGL(k_scan, dim3(1), dim3(1024), 0, stream, cur, N);
  hipLaunchKernelGGL(k_place, dim3(1024), dim3(256), 0, stream, te, cur, sorted, E, N);

  hipLaunchKernelGGL(k_h, dim3(1024), dim3(256), 0, stream, X, wbuf, frags, hb, agg, N);
  hipLaunchKernelGGL(k_edge, dim3(768), dim3(512), 0, stream, sorted, hb, wbuf, frags, agg, E, N);
  hipLaunchKernelGGL(k_nodes, dim3(2048), dim3(256), 0, stream, agg, wbuf, gsum, gmax,
                     ticket, (float*)d_out, N);
}

// Round 8
// 443.197 us; speedup vs baseline: 1.3408x; 1.3408x over previous
//
#include <hip/hip_runtime.h>

typedef unsigned short u16;
typedef unsigned int   u32;
typedef __attribute__((ext_vector_type(8))) short bf16x8;   // 8 bf16 (4 VGPRs)
typedef __attribute__((ext_vector_type(4))) float f32x4;    // mfma acc

#define EPS 1e-5f
#define MFMA(a,b,c) __builtin_amdgcn_mfma_f32_16x16x32_bf16(a,b,c,0,0,0)

// ---- wbuf (fp32) element offsets ----
constexpr int OB_b1=0, OB_g1=64, OB_be1=128, OB_b2=192, OB_bm1=256, OB_w192=320,
              OB_bm2=384, OB_gn=448, OB_bn=512, OB_bg1=576, OB_bg2=640,
              OB_Wg1=704, OB_Wg2=8896, WB_TOT=12992;
// ---- frag buffer (u16/bf16) element offsets ----
constexpr int FR_Wm1=0;          // 24 frags (K=192) = 12288
constexpr int FR_Wm2=12288;      // 8 frags  (K=64)  = 4096
constexpr int FR_rel=16384;      // 7 rows x 80 (pad) = 560, alloc 576
constexpr int FR_W1 =16960;      // 32 frags (K=256) = 16384
constexpr int FR_W2 =33344;      // 8 frags  (K=64)  = 4096
constexpr int FR_TOT=37440;

__device__ __forceinline__ float bf2f(u32 u) { return __uint_as_float(u << 16); }
__device__ __forceinline__ u16 f2bf(float f) {
  u32 b = __float_as_uint(f);
  return (u16)((b + 0x7fffu + ((b >> 16) & 1u)) >> 16);  // RNE
}
__device__ __forceinline__ u32 fkey(float f) {  // monotone float->u32 (finite)
  u32 b = __float_as_uint(f);
  return (b & 0x80000000u) ? ~b : (b | 0x80000000u);
}

// coalesced global->LDS direct copy, 16B/lane (dest = base + lane*16)
__device__ __forceinline__ void gld_lds16(const void* g, void* l) {
  __builtin_amdgcn_global_load_lds(
      (const __attribute__((address_space(1))) void*)g,
      (__attribute__((address_space(3))) void*)l, 16, 0, 0);
}

// ---- prep (+hist fused): wbuf, frag swizzles, dst histogram, zeros ----
__launch_bounds__(256)
__global__ void k_prep(const float* __restrict__ W1, const float* __restrict__ b1,
                       const float* __restrict__ g1, const float* __restrict__ be1,
                       const float* __restrict__ W2, const float* __restrict__ b2,
                       const float* __restrict__ rel_emb,
                       const float* __restrict__ Wm1, const float* __restrict__ bm1,
                       const float* __restrict__ Wm2, const float* __restrict__ bm2,
                       const float* __restrict__ gn, const float* __restrict__ bn,
                       const float* __restrict__ Wg1, const float* __restrict__ bg1,
                       const float* __restrict__ Wg2, const float* __restrict__ bg2,
                       float* __restrict__ wbuf, u16* __restrict__ frags,
                       const float* __restrict__ te, int* __restrict__ cnt,
                       float* __restrict__ gsum, u32* __restrict__ gmax,
                       int* __restrict__ ticket, int E, int N) {
  int tid = blockIdx.x * 256 + threadIdx.x;
  int nth = gridDim.x * 256;
  if (tid == 0) *ticket = 0;
  for (int i = tid; i < 64; i += nth) {
    wbuf[OB_b1 + i] = b1[i];   wbuf[OB_g1 + i] = g1[i];
    wbuf[OB_be1 + i] = be1[i]; wbuf[OB_b2 + i] = b2[i];
    wbuf[OB_bm1 + i] = bm1[i]; wbuf[OB_w192 + i] = Wm1[192 * 64 + i];
    wbuf[OB_bm2 + i] = bm2[i]; wbuf[OB_gn + i] = gn[i];
    wbuf[OB_bn + i] = bn[i];   wbuf[OB_bg1 + i] = bg1[i];
    wbuf[OB_bg2 + i] = bg2[i];
    gsum[i] = 0.f; gmax[i] = 0u;
  }
  for (int i = tid; i < 8192; i += nth) wbuf[OB_Wg1 + i] = Wg1[i];
  for (int i = tid; i < 4096; i += nth) wbuf[OB_Wg2 + i] = Wg2[i];
  for (int idx = tid; idx < 16384; idx += nth) {
    int f = idx >> 9, L = (idx >> 3) & 63, j = idx & 7;
    int k = (f >> 2) * 32 + ((L >> 4) << 3) + j, n = ((f & 3) << 4) + (L & 15);
    frags[FR_W1 + idx] = f2bf(W1[k * 64 + n]);
  }
  for (int idx = tid; idx < 4096; idx += nth) {
    int f = idx >> 9, L = (idx >> 3) & 63, j = idx & 7;
    int k = (f >> 2) * 32 + ((L >> 4) << 3) + j, n = ((f & 3) << 4) + (L & 15);
    frags[FR_W2 + idx] = f2bf(W2[k * 64 + n]);
  }
  for (int idx = tid; idx < 12288; idx += nth) {
    int f = idx >> 9, L = (idx >> 3) & 63, j = idx & 7;
    int k = (f >> 2) * 32 + ((L >> 4) << 3) + j, n = ((f & 3) << 4) + (L & 15);
    frags[FR_Wm1 + idx] = f2bf(Wm1[k * 64 + n]);
  }
  for (int idx = tid; idx < 4096; idx += nth) {
    int f = idx >> 9, L = (idx >> 3) & 63, j = idx & 7;
    int k = (f >> 2) * 32 + ((L >> 4) << 3) + j, n = ((f & 3) << 4) + (L & 15);
    frags[FR_Wm2 + idx] = f2bf(Wm2[k * 64 + n]);
  }
  for (int idx = tid; idx < 576; idx += nth) {
    int r = idx / 80, c = idx % 80;
    frags[FR_rel + idx] = (r < 7 && c < 64) ? f2bf(rel_emb[r * 64 + c]) : (u16)0;
  }
  // fused dst histogram
  for (int e = tid; e < E; e += nth) {
    float4 v = *(const float4*)(te + (size_t)e * 4);
    int d = min(max((int)v.y, 0), N - 1);
    atomicAdd(&cnt[d], 1);
  }
}

// ---- counting sort by dst: multi-block scan chain (proven ~13 us) ----
#define SCH 512
__launch_bounds__(256)
__global__ void k_scan1(const int* __restrict__ cnt, int* __restrict__ bsum, int N) {
  __shared__ int sd[256];
  int b = blockIdx.x, t = threadIdx.x, base = b * SCH;
  int i0 = base + 2 * t, i1 = i0 + 1;
  int a = 0;
  if (i0 < N) a += cnt[i0];
  if (i1 < N) a += cnt[i1];
  sd[t] = a; __syncthreads();
  for (int s = 128; s > 0; s >>= 1) { if (t < s) sd[t] += sd[t + s]; __syncthreads(); }
  if (t == 0) bsum[b] = sd[0];
}

__launch_bounds__(256)
__global__ void k_scan2(const int* __restrict__ bsum, int* __restrict__ bofs, int NBLK) {
  __shared__ int sd[256];
  int t = threadIdx.x;
  int K = (NBLK + 255) / 256;
  int loc = 0;
  for (int k = 0; k < K; k++) { int i = t * K + k; if (i < NBLK) loc += bsum[i]; }
  sd[t] = loc; __syncthreads();
  for (int s = 1; s < 256; s <<= 1) {
    int o = 0; if (t >= s) o = sd[t - s];
    __syncthreads(); sd[t] += o; __syncthreads();
  }
  int excl = sd[t] - loc;
  int run = excl;
  for (int k = 0; k < K; k++) {
    int i = t * K + k;
    if (i < NBLK) { bofs[i] = run; run += bsum[i]; }
  }
}

__launch_bounds__(256)
__global__ void k_scan3(const int* __restrict__ bofs, int* __restrict__ cur, int N) {
  // cur: counts in, exclusive-prefix cursors out
  __shared__ int sd[256];
  int b = blockIdx.x, t = threadIdx.x, base = b * SCH;
  int i0 = base + 2 * t, i1 = i0 + 1;
  int a0 = (i0 < N) ? cur[i0] : 0, a1 = (i1 < N) ? cur[i1] : 0;
  int pair = a0 + a1;
  sd[t] = pair; __syncthreads();
  for (int s = 1; s < 256; s <<= 1) {
    int o = 0; if (t >= s) o = sd[t - s];
    __syncthreads(); sd[t] += o; __syncthreads();
  }
  int excl = sd[t] - pair + bofs[b];
  if (i0 < N) cur[i0] = excl;
  if (i1 < N) cur[i1] = excl + a0;
}

__launch_bounds__(256)
__global__ void k_place(const float* __restrict__ te, int* __restrict__ cur,
                        uint4* __restrict__ sorted, int E, int N) {
  int i = blockIdx.x * 256 + threadIdx.x, st = gridDim.x * 256;
  for (int e = i; e < E; e += st) {
    float4 v = *(const float4*)(te + (size_t)e * 4);
    int s = min(max((int)v.x, 0), N - 1);
    int d = min(max((int)v.y, 0), N - 1);
    int r = min(max((int)v.z, 0), 6);
    int pos = atomicAdd(&cur[d], 1);
    uint4 rec; rec.x = (u32)s; rec.y = (u32)d; rec.z = (u32)r; rec.w = __float_as_uint(v.w);
    sorted[pos] = rec;
  }
}

// ---- stage A (MFMA): h = relu(relu(LN(X@W1+b1)) @ W2 + b2) ----
__launch_bounds__(256, 4)
__global__ void k_h(const float* __restrict__ X, const float* __restrict__ wbuf,
                    const u16* __restrict__ frags, u16* __restrict__ hb,
                    float* __restrict__ agg, int N) {
  __shared__ __align__(16) float xb[2][16 * 256];   // 2 x 16 KB X tile
  __shared__ __align__(16) u16 st[16 * 72];         // bf16 h1 tile (pad 72)
  __shared__ float sred[2][16][4];                  // row {sum,sumsq} per wave

  int lane = threadIdx.x & 63, wave = threadIdx.x >> 6;
  int m = lane & 15, quad = lane >> 4;
  int col = wave * 16 + m;

  bf16x8 bw1[8], bw2[2];
  #pragma unroll
  for (int ks = 0; ks < 8; ks++)
    bw1[ks] = *(const bf16x8*)(frags + FR_W1 + ((ks * 4 + wave) * 64 + lane) * 8);
  #pragma unroll
  for (int ks = 0; ks < 2; ks++)
    bw2[ks] = *(const bf16x8*)(frags + FR_W2 + ((ks * 4 + wave) * 64 + lane) * 8);

  float b1v = wbuf[OB_b1 + col], g1v = wbuf[OB_g1 + col];
  float be1v = wbuf[OB_be1 + col], b2v = wbuf[OB_b2 + col];

  int ntiles = (N + 15) / 16;
  int xorm = (m & 7) << 4;

  auto stage = [&](int t, int buf) {
    int n0s = t * 16;
    #pragma unroll
    for (int i = 0; i < 4; i++) {
      int r = wave * 4 + i;
      int nr = min(n0s + r, N - 1);
      const char* src = (const char*)(X + (size_t)nr * 256);
      int soff = (lane * 16) ^ ((r & 7) << 4);
      gld_lds16(src + soff, (char*)&xb[buf][0] + r * 1024);
    }
  };

  int cur = 0;
  if (blockIdx.x < ntiles) stage(blockIdx.x, 0);

  for (int t = blockIdx.x; t < ntiles; t += gridDim.x) {
    __syncthreads();
    if (t + (int)gridDim.x < ntiles) stage(t + gridDim.x, cur ^ 1);

    int n0 = t * 16;
    const char* xp = (const char*)&xb[cur][0];

    f32x4 acc = {};
    #pragma unroll
    for (int ks = 0; ks < 8; ks++) {
      int base = m * 1024 + ks * 128 + quad * 32;
      float4 u0 = *(const float4*)(xp + (base ^ xorm));
      float4 u1 = *(const float4*)(xp + ((base + 16) ^ xorm));
      bf16x8 a;
      a[0] = (short)f2bf(u0.x); a[1] = (short)f2bf(u0.y);
      a[2] = (short)f2bf(u0.z); a[3] = (short)f2bf(u0.w);
      a[4] = (short)f2bf(u1.x); a[5] = (short)f2bf(u1.y);
      a[6] = (short)f2bf(u1.z); a[7] = (short)f2bf(u1.w);
      acc = MFMA(a, bw1[ks], acc);
    }

    float vv[4];
    #pragma unroll
    for (int r = 0; r < 4; r++) vv[r] = acc[r] + b1v;
    #pragma unroll
    for (int r = 0; r < 4; r++) {
      float s = vv[r], q = vv[r] * vv[r];
      #pragma unroll
      for (int mk = 8; mk >= 1; mk >>= 1) {
        s += __shfl_xor(s, mk, 64);
        q += __shfl_xor(q, mk, 64);
      }
      if (m == 0) { sred[0][quad * 4 + r][wave] = s; sred[1][quad * 4 + r][wave] = q; }
    }
    __syncthreads();
    #pragma unroll
    for (int r = 0; r < 4; r++) {
      int row = quad * 4 + r;
      float4 S = *(const float4*)&sred[0][row][0];
      float4 Q = *(const float4*)&sred[1][row][0];
      float mu = (S.x + S.y + S.z + S.w) * (1.f / 64.f);
      float vq = (Q.x + Q.y + Q.z + Q.w) * (1.f / 64.f) - mu * mu;
      float rs = rsqrtf(fmaxf(vq, 0.f) + EPS);
      float h1 = fmaxf(fmaf((vv[r] - mu) * rs, g1v, be1v), 0.f);
      st[row * 72 + col] = f2bf(h1);
    }
    __syncthreads();

    f32x4 acc2 = {};
    #pragma unroll
    for (int ks = 0; ks < 2; ks++) {
      bf16x8 a2 = *(const bf16x8*)(st + m * 72 + ks * 32 + quad * 8);
      acc2 = MFMA(a2, bw2[ks], acc2);
    }
    #pragma unroll
    for (int r = 0; r < 4; r++) {
      int row = n0 + quad * 4 + r;
      if (row < N) {
        float hv = fmaxf(acc2[r] + b2v, 0.f);
        hb[(size_t)row * 64 + col] = f2bf(hv);
        agg[(size_t)row * 64 + col] = hv;
      }
    }
    cur ^= 1;
  }
}

// ---- stage B+C (MFMA): pipelined edge MLP + shfl-transposed run-reduction ----
__launch_bounds__(512, 5)
__global__ void k_edge(const uint4* __restrict__ sorted, const u16* __restrict__ hb,
                       const float* __restrict__ wbuf, const u16* __restrict__ frags,
                       float* __restrict__ agg, int E, int N) {
  __shared__ __align__(16) u16 sWm1[24 * 512];
  __shared__ __align__(16) u16 sWm2[8 * 512];
  __shared__ __align__(16) u16 srel[576];
  __shared__ __align__(16) u16 stt[8][16 * 72];   // per-wave bf16 t tile

  {
    const uint4* s1 = (const uint4*)(frags + FR_Wm1);
    uint4* d1 = (uint4*)sWm1;
    for (int i = threadIdx.x; i < 1536; i += 512) d1[i] = s1[i];
    const uint4* s2 = (const uint4*)(frags + FR_Wm2);
    uint4* d2 = (uint4*)sWm2;
    for (int i = threadIdx.x; i < 512; i += 512) d2[i] = s2[i];
    const uint4* s3 = (const uint4*)(frags + FR_rel);
    uint4* d3 = (uint4*)srel;
    for (int i = threadIdx.x; i < 72; i += 512) d3[i] = s3[i];
  }
  __syncthreads();

  int lane = threadIdx.x & 63, wave = threadIdx.x >> 6;
  int m = lane & 15, quad = lane >> 4, koff = quad * 8, col0 = m;
  int nthi = lane >> 4;
  u16* stw = stt[wave];

  float bm1v[4], w192v[4], bm2v[4];
  #pragma unroll
  for (int nt = 0; nt < 4; nt++) {
    int c = nt * 16 + col0;
    bm1v[nt] = wbuf[OB_bm1 + c];
    w192v[nt] = wbuf[OB_w192 + c];
    bm2v[nt] = wbuf[OB_bm2 + c];
  }

  int ntiles = (E + 15) >> 4;
  int gw = blockIdx.x * 8 + wave, nwv = gridDim.x * 8;
  int per = (ntiles + nwv - 1) / nwv;
  int tile = gw * per, tend = min(tile + per, ntiles);

  int cd = -1; float cv = 0.f;  // per-lane run carry (lane owns column `lane`)
  int dstv = -1; float wv = 0.f;
  bf16x8 af[6];

  if (tile < tend) {  // prologue: rec + gathers for first tile
    int srcv = 0, relv = 0;
    if (lane < 16) {
      int e = tile * 16 + lane;
      uint4 rc = sorted[min(e, E - 1)];
      srcv = (int)rc.x; dstv = (e < E) ? (int)rc.y : -1;
      relv = (int)rc.z; wv = __uint_as_float(rc.w);
    }
    int sm = __shfl(srcv, m, 64), dmv = __shfl(dstv, m, 64), rm = __shfl(relv, m, 64);
    int dmg = dmv < 0 ? 0 : dmv;
    const u16* hs = hb + (size_t)sm * 64;
    const u16* hd = hb + (size_t)dmg * 64;
    af[0] = *(const bf16x8*)(hs + koff);
    af[1] = *(const bf16x8*)(hs + 32 + koff);
    af[2] = *(const bf16x8*)(hd + koff);
    af[3] = *(const bf16x8*)(hd + 32 + koff);
    af[4] = *(const bf16x8*)(srel + rm * 80 + koff);
    af[5] = *(const bf16x8*)(srel + rm * 80 + 32 + koff);
  }

  for (; tile < tend; tile++) {
    bool hasnext = (tile + 1) < tend;

    // prefetch next sorted rec (full MFMA1 to cover its latency)
    int srcn = 0, dstn = -1, reln = 0; float wn = 0.f;
    if (hasnext && lane < 16) {
      int e = (tile + 1) * 16 + lane;
      uint4 rc = sorted[min(e, E - 1)];
      srcn = (int)rc.x; dstn = (e < E) ? (int)rc.y : -1;
      reln = (int)rc.z; wn = __uint_as_float(rc.w);
    }

    // ---- MFMA1 on current tile ----
    f32x4 acc[4] = {};
    #pragma unroll
    for (int ks = 0; ks < 6; ks++)
      #pragma unroll
      for (int nt = 0; nt < 4; nt++) {
        bf16x8 b = *(const bf16x8*)(sWm1 + (ks * 4 + nt) * 512 + lane * 8);
        acc[nt] = MFMA(af[ks], b, acc[nt]);
      }

    // ---- issue next tile's gathers (af regs free now) ----
    if (hasnext) {
      int sm = __shfl(srcn, m, 64), dmv = __shfl(dstn, m, 64), rm = __shfl(reln, m, 64);
      int dmg = dmv < 0 ? 0 : dmv;
      const u16* hs = hb + (size_t)sm * 64;
      const u16* hd = hb + (size_t)dmg * 64;
      af[0] = *(const bf16x8*)(hs + koff);
      af[1] = *(const bf16x8*)(hs + 32 + koff);
      af[2] = *(const bf16x8*)(hd + koff);
      af[3] = *(const bf16x8*)(hd + 32 + koff);
      af[4] = *(const bf16x8*)(srel + rm * 80 + koff);
      af[5] = *(const bf16x8*)(srel + rm * 80 + 32 + koff);
    }

    // ---- epilogue 1: + bm1 + w*Wm1[192], relu -> bf16 LDS t tile ----
    float wrow[4];
    #pragma unroll
    for (int r = 0; r < 4; r++) wrow[r] = __shfl(wv, quad * 4 + r, 64);
    #pragma unroll
    for (int nt = 0; nt < 4; nt++)
      #pragma unroll
      for (int r = 0; r < 4; r++) {
        float v = fmaf(wrow[r], w192v[nt], acc[nt][r] + bm1v[nt]);
        stw[(quad * 4 + r) * 72 + nt * 16 + col0] = f2bf(fmaxf(v, 0.f));
      }
    __builtin_amdgcn_wave_barrier();

    f32x4 acc2[4] = {};
    #pragma unroll
    for (int ks = 0; ks < 2; ks++) {
      bf16x8 a2 = *(const bf16x8*)(stw + m * 72 + ks * 32 + koff);
      #pragma unroll
      for (int nt = 0; nt < 4; nt++) {
        bf16x8 b = *(const bf16x8*)(sWm2 + (ks * 4 + nt) * 512 + lane * 8);
        acc2[nt] = MFMA(a2, b, acc2[nt]);
      }
    }
    __builtin_amdgcn_wave_barrier();

    // ---- run-reduce: shfl-transpose messages; lane owns column `lane` ----
    #pragma unroll
    for (int r = 0; r < 16; r++) {
      int d = __shfl(dstv, r, 64);
      int sl = ((r >> 2) << 4) + m;
      float c0 = __shfl(acc2[0][r & 3] + bm2v[0], sl, 64);
      float c1 = __shfl(acc2[1][r & 3] + bm2v[1], sl, 64);
      float c2 = __shfl(acc2[2][r & 3] + bm2v[2], sl, 64);
      float c3 = __shfl(acc2[3][r & 3] + bm2v[3], sl, 64);
      float v = nthi == 0 ? c0 : nthi == 1 ? c1 : nthi == 2 ? c2 : c3;
      if (d != cd) {
        if (cd >= 0) atomicAdd(agg + (size_t)cd * 64 + lane, cv);
        cd = d; cv = 0.f;
      }
      if (d >= 0) cv += v;
    }

    dstv = dstn; wv = wn;
  }
  if (cd >= 0) atomicAdd(agg + (size_t)cd * 64 + lane, cv);
}

// ---- stage D1+D2 fused: LN(agg) column sum/max; last block runs final MLP ----
__launch_bounds__(256)
__global__ void k_nodes(const float* __restrict__ agg, const float* __restrict__ wbuf,
                        float* __restrict__ gsum, u32* __restrict__ gmax,
                        int* __restrict__ ticket, float* __restrict__ out, int N) {
  int lane = threadIdx.x & 63, wave = threadIdx.x >> 6;
  int r4 = lane >> 4, c4 = (lane & 15) * 4;
  float4 gnv = *(const float4*)(wbuf + OB_gn + c4);
  float4 bnv = *(const float4*)(wbuf + OB_bn + c4);
  int wid = blockIdx.x * 4 + wave, nw = gridDim.x * 4;
  float sj[4] = {0.f, 0.f, 0.f, 0.f};
  float mj[4] = {-3.0e38f, -3.0e38f, -3.0e38f, -3.0e38f};
  for (int base = wid * 4; base < N; base += nw * 4) {
    int row = base + r4;
    bool ok = row < N;
    float4 av = ok ? *(const float4*)(agg + (size_t)row * 64 + c4)
                   : make_float4(0.f, 0.f, 0.f, 0.f);
    float s = av.x + av.y + av.z + av.w;
    #pragma unroll
    for (int mk = 8; mk >= 1; mk >>= 1) s += __shfl_xor(s, mk, 64);
    float mu = s * (1.f / 64.f);
    float d0 = av.x - mu, d1 = av.y - mu, d2 = av.z - mu, d3 = av.w - mu;
    float q = d0 * d0 + d1 * d1 + d2 * d2 + d3 * d3;
    #pragma unroll
    for (int mk = 8; mk >= 1; mk >>= 1) q += __shfl_xor(q, mk, 64);
    float rs = rsqrtf(q * (1.f / 64.f) + EPS);
    if (ok) {
      float t0 = fmaf(d0 * rs, gnv.x, bnv.x);
      float t1 = fmaf(d1 * rs, gnv.y, bnv.y);
      float t2 = fmaf(d2 * rs, gnv.z, bnv.z);
      float t3 = fmaf(d3 * rs, gnv.w, bnv.w);
      sj[0] += t0; mj[0] = fmaxf(mj[0], t0);
      sj[1] += t1; mj[1] = fmaxf(mj[1], t1);
      sj[2] += t2; mj[2] = fmaxf(mj[2], t2);
      sj[3] += t3; mj[3] = fmaxf(mj[3], t3);
    }
  }
  #pragma unroll
  for (int j = 0; j < 4; j++) {
    sj[j] += __shfl_xor(sj[j], 16, 64);
    sj[j] += __shfl_xor(sj[j], 32, 64);
    mj[j] = fmaxf(mj[j], __shfl_xor(mj[j], 16, 64));
    mj[j] = fmaxf(mj[j], __shfl_xor(mj[j], 32, 64));
  }
  __shared__ float bs[4][64], bm[4][64];
  if (lane < 16) {
    #pragma unroll
    for (int j = 0; j < 4; j++) { bs[wave][c4 + j] = sj[j]; bm[wave][c4 + j] = mj[j]; }
  }
  __syncthreads();
  if (threadIdx.x < 64) {
    int c = threadIdx.x;
    float ts = bs[0][c] + bs[1][c] + bs[2][c] + bs[3][c];
    float tm = fmaxf(fmaxf(bm[0][c], bm[1][c]), fmaxf(bm[2][c], bm[3][c]));
    atomicAdd(gsum + c, ts);
    atomicMax(gmax + c, fkey(tm));
  }
  __syncthreads();

  __shared__ int slast;
  if (threadIdx.x == 0) {
    __threadfence();
    slast = atomicAdd(ticket, 1);
  }
  __syncthreads();
  if (slast == (int)gridDim.x - 1) {   // last block: final 2-layer MLP
    __threadfence();
    __shared__ float g[128];
    __shared__ float y1[64];
    int t = threadIdx.x;
    if (t < 64) {
      g[t] = atomicAdd(gsum + t, 0.f) / (float)N;   // atomic read (coherent)
    } else if (t < 128) {
      u32 k = atomicOr(gmax + (t - 64), 0u);
      u32 b = (k & 0x80000000u) ? (k & 0x7fffffffu) : ~k;
      g[t] = __uint_as_float(b);
    }
    __syncthreads();
    if (t < 64) {
      float a = wbuf[OB_bg1 + t];
      for (int i = 0; i < 128; i++) a = fmaf(g[i], wbuf[OB_Wg1 + i * 64 + t], a);
      y1[t] = fmaxf(a, 0.f);
    }
    __syncthreads();
    if (t < 64) {
      float a = wbuf[OB_bg2 + t];
      for (int k = 0; k < 64; k++) a = fmaf(y1[k], wbuf[OB_Wg2 + k * 64 + t], a);
      out[t] = a;
    }
  }
}

extern "C" void kernel_launch(void* const* d_in, const int* in_sizes, int n_in,
                              void* d_out, int out_size, void* d_ws, size_t ws_size,
                              hipStream_t stream) {
  const int N = in_sizes[0] / 256;
  const int E = in_sizes[1] / 4;
  const int NBLK = (N + SCH - 1) / SCH;

  char* ws = (char*)d_ws;
  size_t p = 0;
  auto rup = [](size_t x) { return (x + 255) & ~(size_t)255; };
  uint4* sorted = (uint4*)(ws + p); p += rup((size_t)E * 16);
  float* agg    = (float*)(ws + p); p += rup((size_t)N * 64 * 4);
  u16*   hb     = (u16*)(ws + p);   p += rup((size_t)N * 128);
  int*   cur    = (int*)(ws + p);   p += rup((size_t)N * 4);
  int*   bsum   = (int*)(ws + p);   p += rup((size_t)(NBLK + 1) * 4);
  int*   bofs   = (int*)(ws + p);   p += rup((size_t)(NBLK + 1) * 4);
  float* gsum   = (float*)(ws + p); p += 256;
  u32*   gmax   = (u32*)(ws + p);   p += 256;
  int*   ticket = (int*)(ws + p);   p += 256;
  float* wbuf   = (float*)(ws + p); p += rup((size_t)WB_TOT * 4);
  u16*   frags  = (u16*)(ws + p);   p += rup((size_t)FR_TOT * 2);

  const float* X  = (const float*)d_in[0];
  const float* te = (const float*)d_in[1];

  hipMemsetAsync(cur, 0, (size_t)N * 4, stream);
  hipLaunchKernelGGL(k_prep, dim3(1024), dim3(256), 0, stream,
                     (const float*)d_in[2], (const float*)d_in[3], (const float*)d_in[4],
                     (const float*)d_in[5], (const float*)d_in[6], (const float*)d_in[7],
                     (const float*)d_in[8], (const float*)d_in[9], (const float*)d_in[10],
                     (const float*)d_in[11], (const float*)d_in[12], (const float*)d_in[13],
                     (const float*)d_in[14], (const float*)d_in[15], (const float*)d_in[16],
                     (const float*)d_in[17], (const float*)d_in[18], wbuf, frags,
                     te, cur, gsum, gmax, ticket, E, N);

  hipLaunchKernelGGL(k_scan1, dim3(NBLK), dim3(256), 0, stream, cur, bsum, N);
  hipLaunchKernelGGL(k_scan2, dim3(1), dim3(256), 0, stream, bsum, bofs, NBLK);
  hipLaunchKernelGGL(k_scan3, dim3(NBLK), dim3(256), 0, stream, bofs, cur, N);
  hipLaunchKernelGGL(k_place, dim3(1024), dim3(256), 0, stream, te, cur, sorted, E, N);

  hipLaunchKernelGGL(k_h, dim3(1024), dim3(256), 0, stream, X, wbuf, frags, hb, agg, N);
  hipLaunchKernelGGL(k_edge, dim3(768), dim3(512), 0, stream, sorted, hb, wbuf, frags, agg, E, N);
  hipLaunchKernelGGL(k_nodes, dim3(2048), dim3(256), 0, stream, agg, wbuf, gsum, gmax,
                     ticket, (float*)d_out, N);
}

// Round 9
// 417.992 us; speedup vs baseline: 1.4217x; 1.0603x over previous
//
#include <hip/hip_runtime.h>

typedef unsigned short u16;
typedef unsigned int   u32;
typedef __attribute__((ext_vector_type(8))) short bf16x8;   // 8 bf16 (4 VGPRs)
typedef __attribute__((ext_vector_type(4))) float f32x4;    // mfma acc

#define EPS 1e-5f
#define MFMA(a,b,c) __builtin_amdgcn_mfma_f32_16x16x32_bf16(a,b,c,0,0,0)

// ---- wbuf (fp32) element offsets ----
constexpr int OB_b1=0, OB_g1=64, OB_be1=128, OB_b2=192, OB_bm1=256, OB_w192=320,
              OB_bm2=384, OB_gn=448, OB_bn=512, OB_bg1=576, OB_bg2=640,
              OB_Wg1=704, OB_Wg2=8896, WB_TOT=12992;
// ---- frag buffer (u16/bf16) element offsets ----
constexpr int FR_Wm1=0;          // 24 frags (K=192) = 12288
constexpr int FR_Wm2=12288;      // 8 frags  (K=64)  = 4096
constexpr int FR_rel=16384;      // 7 rows x 80 (pad) = 560, alloc 576
constexpr int FR_W1 =16960;      // 32 frags (K=256) = 16384
constexpr int FR_W2 =33344;      // 8 frags  (K=64)  = 4096
constexpr int FR_TOT=37440;

__device__ __forceinline__ float bf2f(u32 u) { return __uint_as_float(u << 16); }
__device__ __forceinline__ u16 f2bf(float f) {
  u32 b = __float_as_uint(f);
  return (u16)((b + 0x7fffu + ((b >> 16) & 1u)) >> 16);  // RNE
}
__device__ __forceinline__ u32 fkey(float f) {  // monotone float->u32 (finite)
  u32 b = __float_as_uint(f);
  return (b & 0x80000000u) ? ~b : (b | 0x80000000u);
}

// coalesced global->LDS direct copy, 16B/lane (dest = base + lane*16)
__device__ __forceinline__ void gld_lds16(const void* g, void* l) {
  __builtin_amdgcn_global_load_lds(
      (const __attribute__((address_space(1))) void*)g,
      (__attribute__((address_space(3))) void*)l, 16, 0, 0);
}

// ---- prep (+hist fused): wbuf, frag swizzles, dst histogram, zeros ----
__launch_bounds__(256)
__global__ void k_prep(const float* __restrict__ W1, const float* __restrict__ b1,
                       const float* __restrict__ g1, const float* __restrict__ be1,
                       const float* __restrict__ W2, const float* __restrict__ b2,
                       const float* __restrict__ rel_emb,
                       const float* __restrict__ Wm1, const float* __restrict__ bm1,
                       const float* __restrict__ Wm2, const float* __restrict__ bm2,
                       const float* __restrict__ gn, const float* __restrict__ bn,
                       const float* __restrict__ Wg1, const float* __restrict__ bg1,
                       const float* __restrict__ Wg2, const float* __restrict__ bg2,
                       float* __restrict__ wbuf, u16* __restrict__ frags,
                       const float* __restrict__ te, int* __restrict__ cnt,
                       float* __restrict__ gsum, u32* __restrict__ gmax,
                       int* __restrict__ ticket, int E, int N) {
  int tid = blockIdx.x * 256 + threadIdx.x;
  int nth = gridDim.x * 256;
  if (tid == 0) *ticket = 0;
  for (int i = tid; i < 64; i += nth) {
    wbuf[OB_b1 + i] = b1[i];   wbuf[OB_g1 + i] = g1[i];
    wbuf[OB_be1 + i] = be1[i]; wbuf[OB_b2 + i] = b2[i];
    wbuf[OB_bm1 + i] = bm1[i]; wbuf[OB_w192 + i] = Wm1[192 * 64 + i];
    wbuf[OB_bm2 + i] = bm2[i]; wbuf[OB_gn + i] = gn[i];
    wbuf[OB_bn + i] = bn[i];   wbuf[OB_bg1 + i] = bg1[i];
    wbuf[OB_bg2 + i] = bg2[i];
    gsum[i] = 0.f; gmax[i] = 0u;
  }
  for (int i = tid; i < 8192; i += nth) wbuf[OB_Wg1 + i] = Wg1[i];
  for (int i = tid; i < 4096; i += nth) wbuf[OB_Wg2 + i] = Wg2[i];
  for (int idx = tid; idx < 16384; idx += nth) {
    int f = idx >> 9, L = (idx >> 3) & 63, j = idx & 7;
    int k = (f >> 2) * 32 + ((L >> 4) << 3) + j, n = ((f & 3) << 4) + (L & 15);
    frags[FR_W1 + idx] = f2bf(W1[k * 64 + n]);
  }
  for (int idx = tid; idx < 4096; idx += nth) {
    int f = idx >> 9, L = (idx >> 3) & 63, j = idx & 7;
    int k = (f >> 2) * 32 + ((L >> 4) << 3) + j, n = ((f & 3) << 4) + (L & 15);
    frags[FR_W2 + idx] = f2bf(W2[k * 64 + n]);
  }
  for (int idx = tid; idx < 12288; idx += nth) {
    int f = idx >> 9, L = (idx >> 3) & 63, j = idx & 7;
    int k = (f >> 2) * 32 + ((L >> 4) << 3) + j, n = ((f & 3) << 4) + (L & 15);
    frags[FR_Wm1 + idx] = f2bf(Wm1[k * 64 + n]);
  }
  for (int idx = tid; idx < 4096; idx += nth) {
    int f = idx >> 9, L = (idx >> 3) & 63, j = idx & 7;
    int k = (f >> 2) * 32 + ((L >> 4) << 3) + j, n = ((f & 3) << 4) + (L & 15);
    frags[FR_Wm2 + idx] = f2bf(Wm2[k * 64 + n]);
  }
  for (int idx = tid; idx < 576; idx += nth) {
    int r = idx / 80, c = idx % 80;
    frags[FR_rel + idx] = (r < 7 && c < 64) ? f2bf(rel_emb[r * 64 + c]) : (u16)0;
  }
  // fused dst histogram
  for (int e = tid; e < E; e += nth) {
    float4 v = *(const float4*)(te + (size_t)e * 4);
    int d = min(max((int)v.y, 0), N - 1);
    atomicAdd(&cnt[d], 1);
  }
}

// ---- counting sort by dst: multi-block scan chain ----
#define SCH 512
__launch_bounds__(256)
__global__ void k_scan1(const int* __restrict__ cnt, int* __restrict__ bsum, int N) {
  __shared__ int sd[256];
  int b = blockIdx.x, t = threadIdx.x, base = b * SCH;
  int i0 = base + 2 * t, i1 = i0 + 1;
  int a = 0;
  if (i0 < N) a += cnt[i0];
  if (i1 < N) a += cnt[i1];
  sd[t] = a; __syncthreads();
  for (int s = 128; s > 0; s >>= 1) { if (t < s) sd[t] += sd[t + s]; __syncthreads(); }
  if (t == 0) bsum[b] = sd[0];
}

__launch_bounds__(256)
__global__ void k_scan2(const int* __restrict__ bsum, int* __restrict__ bofs, int NBLK) {
  __shared__ int sd[256];
  int t = threadIdx.x;
  int K = (NBLK + 255) / 256;
  int loc = 0;
  for (int k = 0; k < K; k++) { int i = t * K + k; if (i < NBLK) loc += bsum[i]; }
  sd[t] = loc; __syncthreads();
  for (int s = 1; s < 256; s <<= 1) {
    int o = 0; if (t >= s) o = sd[t - s];
    __syncthreads(); sd[t] += o; __syncthreads();
  }
  int excl = sd[t] - loc;
  int run = excl;
  for (int k = 0; k < K; k++) {
    int i = t * K + k;
    if (i < NBLK) { bofs[i] = run; run += bsum[i]; }
  }
}

__launch_bounds__(256)
__global__ void k_scan3(const int* __restrict__ bofs, int* __restrict__ cur, int N) {
  // cur: counts in, exclusive-prefix cursors out
  __shared__ int sd[256];
  int b = blockIdx.x, t = threadIdx.x, base = b * SCH;
  int i0 = base + 2 * t, i1 = i0 + 1;
  int a0 = (i0 < N) ? cur[i0] : 0, a1 = (i1 < N) ? cur[i1] : 0;
  int pair = a0 + a1;
  sd[t] = pair; __syncthreads();
  for (int s = 1; s < 256; s <<= 1) {
    int o = 0; if (t >= s) o = sd[t - s];
    __syncthreads(); sd[t] += o; __syncthreads();
  }
  int excl = sd[t] - pair + bofs[b];
  if (i0 < N) cur[i0] = excl;
  if (i1 < N) cur[i1] = excl + a0;
}

__launch_bounds__(256)
__global__ void k_place(const float* __restrict__ te, int* __restrict__ cur,
                        uint4* __restrict__ sorted, int E, int N) {
  int i = blockIdx.x * 256 + threadIdx.x, st = gridDim.x * 256;
  for (int e = i; e < E; e += st) {
    float4 v = *(const float4*)(te + (size_t)e * 4);
    int s = min(max((int)v.x, 0), N - 1);
    int d = min(max((int)v.y, 0), N - 1);
    int r = min(max((int)v.z, 0), 6);
    int pos = atomicAdd(&cur[d], 1);
    uint4 rec; rec.x = (u32)s; rec.y = (u32)d; rec.z = (u32)r; rec.w = __float_as_uint(v.w);
    sorted[pos] = rec;
  }
}

// ---- stage A (MFMA): h = relu(relu(LN(X@W1+b1)) @ W2 + b2) ----
__launch_bounds__(256, 4)
__global__ void k_h(const float* __restrict__ X, const float* __restrict__ wbuf,
                    const u16* __restrict__ frags, u16* __restrict__ hb,
                    float* __restrict__ agg, int N) {
  __shared__ __align__(16) float xb[2][16 * 256];   // 2 x 16 KB X tile
  __shared__ __align__(16) u16 st[16 * 72];         // bf16 h1 tile (pad 72)
  __shared__ float sred[2][16][4];                  // row {sum,sumsq} per wave

  int lane = threadIdx.x & 63, wave = threadIdx.x >> 6;
  int m = lane & 15, quad = lane >> 4;
  int col = wave * 16 + m;

  bf16x8 bw1[8], bw2[2];
  #pragma unroll
  for (int ks = 0; ks < 8; ks++)
    bw1[ks] = *(const bf16x8*)(frags + FR_W1 + ((ks * 4 + wave) * 64 + lane) * 8);
  #pragma unroll
  for (int ks = 0; ks < 2; ks++)
    bw2[ks] = *(const bf16x8*)(frags + FR_W2 + ((ks * 4 + wave) * 64 + lane) * 8);

  float b1v = wbuf[OB_b1 + col], g1v = wbuf[OB_g1 + col];
  float be1v = wbuf[OB_be1 + col], b2v = wbuf[OB_b2 + col];

  int ntiles = (N + 15) / 16;
  int xorm = (m & 7) << 4;

  auto stage = [&](int t, int buf) {
    int n0s = t * 16;
    #pragma unroll
    for (int i = 0; i < 4; i++) {
      int r = wave * 4 + i;
      int nr = min(n0s + r, N - 1);
      const char* src = (const char*)(X + (size_t)nr * 256);
      int soff = (lane * 16) ^ ((r & 7) << 4);
      gld_lds16(src + soff, (char*)&xb[buf][0] + r * 1024);
    }
  };

  int cur = 0;
  if (blockIdx.x < ntiles) stage(blockIdx.x, 0);

  for (int t = blockIdx.x; t < ntiles; t += gridDim.x) {
    __syncthreads();
    if (t + (int)gridDim.x < ntiles) stage(t + gridDim.x, cur ^ 1);

    int n0 = t * 16;
    const char* xp = (const char*)&xb[cur][0];

    f32x4 acc = {};
    #pragma unroll
    for (int ks = 0; ks < 8; ks++) {
      int base = m * 1024 + ks * 128 + quad * 32;
      float4 u0 = *(const float4*)(xp + (base ^ xorm));
      float4 u1 = *(const float4*)(xp + ((base + 16) ^ xorm));
      bf16x8 a;
      a[0] = (short)f2bf(u0.x); a[1] = (short)f2bf(u0.y);
      a[2] = (short)f2bf(u0.z); a[3] = (short)f2bf(u0.w);
      a[4] = (short)f2bf(u1.x); a[5] = (short)f2bf(u1.y);
      a[6] = (short)f2bf(u1.z); a[7] = (short)f2bf(u1.w);
      acc = MFMA(a, bw1[ks], acc);
    }

    float vv[4];
    #pragma unroll
    for (int r = 0; r < 4; r++) vv[r] = acc[r] + b1v;
    #pragma unroll
    for (int r = 0; r < 4; r++) {
      float s = vv[r], q = vv[r] * vv[r];
      #pragma unroll
      for (int mk = 8; mk >= 1; mk >>= 1) {
        s += __shfl_xor(s, mk, 64);
        q += __shfl_xor(q, mk, 64);
      }
      if (m == 0) { sred[0][quad * 4 + r][wave] = s; sred[1][quad * 4 + r][wave] = q; }
    }
    __syncthreads();
    #pragma unroll
    for (int r = 0; r < 4; r++) {
      int row = quad * 4 + r;
      float4 S = *(const float4*)&sred[0][row][0];
      float4 Q = *(const float4*)&sred[1][row][0];
      float mu = (S.x + S.y + S.z + S.w) * (1.f / 64.f);
      float vq = (Q.x + Q.y + Q.z + Q.w) * (1.f / 64.f) - mu * mu;
      float rs = rsqrtf(fmaxf(vq, 0.f) + EPS);
      float h1 = fmaxf(fmaf((vv[r] - mu) * rs, g1v, be1v), 0.f);
      st[row * 72 + col] = f2bf(h1);
    }
    __syncthreads();

    f32x4 acc2 = {};
    #pragma unroll
    for (int ks = 0; ks < 2; ks++) {
      bf16x8 a2 = *(const bf16x8*)(st + m * 72 + ks * 32 + quad * 8);
      acc2 = MFMA(a2, bw2[ks], acc2);
    }
    #pragma unroll
    for (int r = 0; r < 4; r++) {
      int row = n0 + quad * 4 + r;
      if (row < N) {
        float hv = fmaxf(acc2[r] + b2v, 0.f);
        hb[(size_t)row * 64 + col] = f2bf(hv);
        agg[(size_t)row * 64 + col] = hv;
      }
    }
    cur ^= 1;
  }
}

// ---- stage B+C (MFMA): edge MLP, gather-pipelined, LDS-tile run-reduction ----
// Round-6 reduce (f32 LDS tile, columnar reads, no shfl chains) + round-7
// gather pipelining (next rec before MFMA1, next gathers after MFMA1).
__launch_bounds__(512, 4)
__global__ void k_edge(const uint4* __restrict__ sorted, const u16* __restrict__ hb,
                       const float* __restrict__ wbuf, const u16* __restrict__ frags,
                       float* __restrict__ agg, int E, int N) {
  __shared__ __align__(16) u16 sWm1[24 * 512];
  __shared__ __align__(16) u16 sWm2[8 * 512];
  __shared__ __align__(16) u16 srel[576];
  __shared__ __align__(16) float st32[8][16 * 68];  // per-wave f32 tile (t, then out)
  __shared__ int sdst[8][16];

  {
    const uint4* s1 = (const uint4*)(frags + FR_Wm1);
    uint4* d1 = (uint4*)sWm1;
    for (int i = threadIdx.x; i < 1536; i += 512) d1[i] = s1[i];
    const uint4* s2 = (const uint4*)(frags + FR_Wm2);
    uint4* d2 = (uint4*)sWm2;
    for (int i = threadIdx.x; i < 512; i += 512) d2[i] = s2[i];
    const uint4* s3 = (const uint4*)(frags + FR_rel);
    uint4* d3 = (uint4*)srel;
    for (int i = threadIdx.x; i < 72; i += 512) d3[i] = s3[i];
  }
  __syncthreads();

  int lane = threadIdx.x & 63, wave = threadIdx.x >> 6;
  int m = lane & 15, quad = lane >> 4, koff = quad * 8, col0 = m;
  float* st = st32[wave];
  int* dstS = sdst[wave];

  float bm1v[4], w192v[4], bm2v[4];
  #pragma unroll
  for (int nt = 0; nt < 4; nt++) {
    int c = nt * 16 + col0;
    bm1v[nt] = wbuf[OB_bm1 + c];
    w192v[nt] = wbuf[OB_w192 + c];
    bm2v[nt] = wbuf[OB_bm2 + c];
  }

  int ntiles = (E + 15) >> 4;
  int gw = blockIdx.x * 8 + wave, nwv = gridDim.x * 8;
  int per = (ntiles + nwv - 1) / nwv;
  int tile = gw * per, tend = min(tile + per, ntiles);

  int cd = -1; float cv = 0.f;  // per-lane run carry (lane owns column `lane`)
  int dstv = -1; float wv = 0.f;
  bf16x8 af[6];

  if (tile < tend) {  // prologue: rec + gathers for first tile
    int srcv = 0, relv = 0;
    if (lane < 16) {
      int e = tile * 16 + lane;
      uint4 rc = sorted[min(e, E - 1)];
      srcv = (int)rc.x; dstv = (e < E) ? (int)rc.y : -1;
      relv = (int)rc.z; wv = __uint_as_float(rc.w);
    }
    int sm = __shfl(srcv, m, 64), dmv = __shfl(dstv, m, 64), rm = __shfl(relv, m, 64);
    int dmg = dmv < 0 ? 0 : dmv;
    const u16* hs = hb + (size_t)sm * 64;
    const u16* hd = hb + (size_t)dmg * 64;
    af[0] = *(const bf16x8*)(hs + koff);
    af[1] = *(const bf16x8*)(hs + 32 + koff);
    af[2] = *(const bf16x8*)(hd + koff);
    af[3] = *(const bf16x8*)(hd + 32 + koff);
    af[4] = *(const bf16x8*)(srel + rm * 80 + koff);
    af[5] = *(const bf16x8*)(srel + rm * 80 + 32 + koff);
  }

  for (; tile < tend; tile++) {
    bool hasnext = (tile + 1) < tend;

    // current tile's dst codes -> LDS (consumed by the run-reduce below)
    if (lane < 16) dstS[lane] = dstv;

    // prefetch next sorted rec (MFMA1 covers its latency)
    int srcn = 0, dstn = -1, reln = 0; float wn = 0.f;
    if (hasnext && lane < 16) {
      int e = (tile + 1) * 16 + lane;
      uint4 rc = sorted[min(e, E - 1)];
      srcn = (int)rc.x; dstn = (e < E) ? (int)rc.y : -1;
      reln = (int)rc.z; wn = __uint_as_float(rc.w);
    }

    // ---- MFMA1 on current tile ----
    f32x4 acc[4] = {};
    #pragma unroll
    for (int ks = 0; ks < 6; ks++)
      #pragma unroll
      for (int nt = 0; nt < 4; nt++) {
        bf16x8 b = *(const bf16x8*)(sWm1 + (ks * 4 + nt) * 512 + lane * 8);
        acc[nt] = MFMA(af[ks], b, acc[nt]);
      }

    // ---- issue next tile's gathers (af regs free now) ----
    if (hasnext) {
      int sm = __shfl(srcn, m, 64), dmv = __shfl(dstn, m, 64), rm = __shfl(reln, m, 64);
      int dmg = dmv < 0 ? 0 : dmv;
      const u16* hs = hb + (size_t)sm * 64;
      const u16* hd = hb + (size_t)dmg * 64;
      af[0] = *(const bf16x8*)(hs + koff);
      af[1] = *(const bf16x8*)(hs + 32 + koff);
      af[2] = *(const bf16x8*)(hd + koff);
      af[3] = *(const bf16x8*)(hd + 32 + koff);
      af[4] = *(const bf16x8*)(srel + rm * 80 + koff);
      af[5] = *(const bf16x8*)(srel + rm * 80 + 32 + koff);
    }

    // ---- epilogue 1: + bm1 + w*Wm1[192], relu -> f32 LDS tile (t) ----
    float wrow[4];
    #pragma unroll
    for (int r = 0; r < 4; r++) wrow[r] = __shfl(wv, quad * 4 + r, 64);
    #pragma unroll
    for (int nt = 0; nt < 4; nt++)
      #pragma unroll
      for (int r = 0; r < 4; r++) {
        float v = fmaf(wrow[r], w192v[nt], acc[nt][r] + bm1v[nt]);
        st[(quad * 4 + r) * 68 + nt * 16 + col0] = fmaxf(v, 0.f);
      }
    __builtin_amdgcn_wave_barrier();

    f32x4 acc2[4] = {};
    #pragma unroll
    for (int ks = 0; ks < 2; ks++) {
      float4 p0 = *(const float4*)(st + m * 68 + ks * 32 + koff);
      float4 p1 = *(const float4*)(st + m * 68 + ks * 32 + koff + 4);
      bf16x8 a2;
      a2[0] = (short)f2bf(p0.x); a2[1] = (short)f2bf(p0.y);
      a2[2] = (short)f2bf(p0.z); a2[3] = (short)f2bf(p0.w);
      a2[4] = (short)f2bf(p1.x); a2[5] = (short)f2bf(p1.y);
      a2[6] = (short)f2bf(p1.z); a2[7] = (short)f2bf(p1.w);
      #pragma unroll
      for (int nt = 0; nt < 4; nt++) {
        bf16x8 b = *(const bf16x8*)(sWm2 + (ks * 4 + nt) * 512 + lane * 8);
        acc2[nt] = MFMA(a2, b, acc2[nt]);
      }
    }
    __builtin_amdgcn_wave_barrier();

    // overwrite the f32 tile with the output messages (+bm2)
    #pragma unroll
    for (int nt = 0; nt < 4; nt++)
      #pragma unroll
      for (int r = 0; r < 4; r++)
        st[(quad * 4 + r) * 68 + nt * 16 + col0] = acc2[nt][r] + bm2v[nt];
    __builtin_amdgcn_wave_barrier();

    // columnar segmented run-reduction; one coalesced atomic per run boundary
    #pragma unroll
    for (int r = 0; r < 16; r++) {
      int d = dstS[r];
      float v = st[r * 68 + lane];
      if (d != cd) {
        if (cd >= 0) atomicAdd(agg + (size_t)cd * 64 + lane, cv);
        cd = d; cv = 0.f;
      }
      if (d >= 0) cv += v;
    }
    __builtin_amdgcn_wave_barrier();

    dstv = dstn; wv = wn;
  }
  if (cd >= 0) atomicAdd(agg + (size_t)cd * 64 + lane, cv);
}

// ---- stage D1+D2 fused: LN(agg) column sum/max; last block runs final MLP ----
__launch_bounds__(256)
__global__ void k_nodes(const float* __restrict__ agg, const float* __restrict__ wbuf,
                        float* __restrict__ gsum, u32* __restrict__ gmax,
                        int* __restrict__ ticket, float* __restrict__ out, int N) {
  int lane = threadIdx.x & 63, wave = threadIdx.x >> 6;
  int r4 = lane >> 4, c4 = (lane & 15) * 4;
  float4 gnv = *(const float4*)(wbuf + OB_gn + c4);
  float4 bnv = *(const float4*)(wbuf + OB_bn + c4);
  int wid = blockIdx.x * 4 + wave, nw = gridDim.x * 4;
  float sj[4] = {0.f, 0.f, 0.f, 0.f};
  float mj[4] = {-3.0e38f, -3.0e38f, -3.0e38f, -3.0e38f};
  for (int base = wid * 4; base < N; base += nw * 4) {
    int row = base + r4;
    bool ok = row < N;
    float4 av = ok ? *(const float4*)(agg + (size_t)row * 64 + c4)
                   : make_float4(0.f, 0.f, 0.f, 0.f);
    float s = av.x + av.y + av.z + av.w;
    #pragma unroll
    for (int mk = 8; mk >= 1; mk >>= 1) s += __shfl_xor(s, mk, 64);
    float mu = s * (1.f / 64.f);
    float d0 = av.x - mu, d1 = av.y - mu, d2 = av.z - mu, d3 = av.w - mu;
    float q = d0 * d0 + d1 * d1 + d2 * d2 + d3 * d3;
    #pragma unroll
    for (int mk = 8; mk >= 1; mk >>= 1) q += __shfl_xor(q, mk, 64);
    float rs = rsqrtf(q * (1.f / 64.f) + EPS);
    if (ok) {
      float t0 = fmaf(d0 * rs, gnv.x, bnv.x);
      float t1 = fmaf(d1 * rs, gnv.y, bnv.y);
      float t2 = fmaf(d2 * rs, gnv.z, bnv.z);
      float t3 = fmaf(d3 * rs, gnv.w, bnv.w);
      sj[0] += t0; mj[0] = fmaxf(mj[0], t0);
      sj[1] += t1; mj[1] = fmaxf(mj[1], t1);
      sj[2] += t2; mj[2] = fmaxf(mj[2], t2);
      sj[3] += t3; mj[3] = fmaxf(mj[3], t3);
    }
  }
  #pragma unroll
  for (int j = 0; j < 4; j++) {
    sj[j] += __shfl_xor(sj[j], 16, 64);
    sj[j] += __shfl_xor(sj[j], 32, 64);
    mj[j] = fmaxf(mj[j], __shfl_xor(mj[j], 16, 64));
    mj[j] = fmaxf(mj[j], __shfl_xor(mj[j], 32, 64));
  }
  __shared__ float bs[4][64], bm[4][64];
  if (lane < 16) {
    #pragma unroll
    for (int j = 0; j < 4; j++) { bs[wave][c4 + j] = sj[j]; bm[wave][c4 + j] = mj[j]; }
  }
  __syncthreads();
  if (threadIdx.x < 64) {
    int c = threadIdx.x;
    float ts = bs[0][c] + bs[1][c] + bs[2][c] + bs[3][c];
    float tm = fmaxf(fmaxf(bm[0][c], bm[1][c]), fmaxf(bm[2][c], bm[3][c]));
    atomicAdd(gsum + c, ts);
    atomicMax(gmax + c, fkey(tm));
  }
  __syncthreads();

  __shared__ int slast;
  if (threadIdx.x == 0) {
    __threadfence();
    slast = atomicAdd(ticket, 1);
  }
  __syncthreads();
  if (slast == (int)gridDim.x - 1) {   // last block: final 2-layer MLP
    __threadfence();
    __shared__ float g[128];
    __shared__ float y1[64];
    int t = threadIdx.x;
    if (t < 64) {
      g[t] = atomicAdd(gsum + t, 0.f) / (float)N;   // atomic read (coherent)
    } else if (t < 128) {
      u32 k = atomicOr(gmax + (t - 64), 0u);
      u32 b = (k & 0x80000000u) ? (k & 0x7fffffffu) : ~k;
      g[t] = __uint_as_float(b);
    }
    __syncthreads();
    if (t < 64) {
      float a = wbuf[OB_bg1 + t];
      for (int i = 0; i < 128; i++) a = fmaf(g[i], wbuf[OB_Wg1 + i * 64 + t], a);
      y1[t] = fmaxf(a, 0.f);
    }
    __syncthreads();
    if (t < 64) {
      float a = wbuf[OB_bg2 + t];
      for (int k = 0; k < 64; k++) a = fmaf(y1[k], wbuf[OB_Wg2 + k * 64 + t], a);
      out[t] = a;
    }
  }
}

extern "C" void kernel_launch(void* const* d_in, const int* in_sizes, int n_in,
                              void* d_out, int out_size, void* d_ws, size_t ws_size,
                              hipStream_t stream) {
  const int N = in_sizes[0] / 256;
  const int E = in_sizes[1] / 4;
  const int NBLK = (N + SCH - 1) / SCH;

  char* ws = (char*)d_ws;
  size_t p = 0;
  auto rup = [](size_t x) { return (x + 255) & ~(size_t)255; };
  uint4* sorted = (uint4*)(ws + p); p += rup((size_t)E * 16);
  float* agg    = (float*)(ws + p); p += rup((size_t)N * 64 * 4);
  u16*   hb     = (u16*)(ws + p);   p += rup((size_t)N * 128);
  int*   cur    = (int*)(ws + p);   p += rup((size_t)N * 4);
  int*   bsum   = (int*)(ws + p);   p += rup((size_t)(NBLK + 1) * 4);
  int*   bofs   = (int*)(ws + p);   p += rup((size_t)(NBLK + 1) * 4);
  float* gsum   = (float*)(ws + p); p += 256;
  u32*   gmax   = (u32*)(ws + p);   p += 256;
  int*   ticket = (int*)(ws + p);   p += 256;
  float* wbuf   = (float*)(ws + p); p += rup((size_t)WB_TOT * 4);
  u16*   frags  = (u16*)(ws + p);   p += rup((size_t)FR_TOT * 2);

  const float* X  = (const float*)d_in[0];
  const float* te = (const float*)d_in[1];

  hipMemsetAsync(cur, 0, (size_t)N * 4, stream);
  hipLaunchKernelGGL(k_prep, dim3(1024), dim3(256), 0, stream,
                     (const float*)d_in[2], (const float*)d_in[3], (const float*)d_in[4],
                     (const float*)d_in[5], (const float*)d_in[6], (const float*)d_in[7],
                     (const float*)d_in[8], (const float*)d_in[9], (const float*)d_in[10],
                     (const float*)d_in[11], (const float*)d_in[12], (const float*)d_in[13],
                     (const float*)d_in[14], (const float*)d_in[15], (const float*)d_in[16],
                     (const float*)d_in[17], (const float*)d_in[18], wbuf, frags,
                     te, cur, gsum, gmax, ticket, E, N);

  hipLaunchKernelGGL(k_scan1, dim3(NBLK), dim3(256), 0, stream, cur, bsum, N);
  hipLaunchKernelGGL(k_scan2, dim3(1), dim3(256), 0, stream, bsum, bofs, NBLK);
  hipLaunchKernelGGL(k_scan3, dim3(NBLK), dim3(256), 0, stream, bofs, cur, N);
  hipLaunchKernelGGL(k_place, dim3(1024), dim3(256), 0, stream, te, cur, sorted, E, N);

  hipLaunchKernelGGL(k_h, dim3(1024), dim3(256), 0, stream, X, wbuf, frags, hb, agg, N);
  hipLaunchKernelGGL(k_edge, dim3(512), dim3(512), 0, stream, sorted, hb, wbuf, frags, agg, E, N);
  hipLaunchKernelGGL(k_nodes, dim3(2048), dim3(256), 0, stream, agg, wbuf, gsum, gmax,
                     ticket, (float*)d_out, N);
}

// Round 10
// 366.533 us; speedup vs baseline: 1.6212x; 1.1404x over previous
//
#include <hip/hip_runtime.h>

typedef unsigned short u16;
typedef unsigned int   u32;
typedef __attribute__((ext_vector_type(8))) short bf16x8;   // 8 bf16 (4 VGPRs)
typedef __attribute__((ext_vector_type(4))) float f32x4;    // mfma acc

#define EPS 1e-5f
#define MFMA(a,b,c) __builtin_amdgcn_mfma_f32_16x16x32_bf16(a,b,c,0,0,0)

// ---- wbuf (fp32) element offsets ----
constexpr int OB_b1=0, OB_g1=64, OB_be1=128, OB_b2=192, OB_bm1=256, OB_w192=320,
              OB_bm2=384, OB_gn=448, OB_bn=512, OB_bg1=576, OB_bg2=640,
              OB_Wg1=704, OB_Wg2=8896, WB_TOT=12992;
// ---- frag buffer (u16/bf16) element offsets ----
constexpr int FR_Wm1=0;          // 24 frags (K=192) = 12288
constexpr int FR_Wm2=12288;      // 8 frags  (K=64)  = 4096
constexpr int FR_rel=16384;      // 7 rows x 80 (pad) = 560, alloc 576
constexpr int FR_W1 =16960;      // 32 frags (K=256) = 16384
constexpr int FR_W2 =33344;      // 8 frags  (K=64)  = 4096
constexpr int FR_TOT=37440;

__device__ __forceinline__ float bf2f(u32 u) { return __uint_as_float(u << 16); }
__device__ __forceinline__ u16 f2bf(float f) {
  u32 b = __float_as_uint(f);
  return (u16)((b + 0x7fffu + ((b >> 16) & 1u)) >> 16);  // RNE
}
__device__ __forceinline__ u32 fkey(float f) {  // monotone float->u32 (finite)
  u32 b = __float_as_uint(f);
  return (b & 0x80000000u) ? ~b : (b | 0x80000000u);
}

// coalesced global->LDS direct copy, 16B/lane (dest = base + lane*16)
__device__ __forceinline__ void gld_lds16(const void* g, void* l) {
  __builtin_amdgcn_global_load_lds(
      (const __attribute__((address_space(1))) void*)g,
      (__attribute__((address_space(3))) void*)l, 16, 0, 0);
}

// ---- prep (+hist fused): wbuf, frag swizzles, dst histogram, zeros ----
__launch_bounds__(256)
__global__ void k_prep(const float* __restrict__ W1, const float* __restrict__ b1,
                       const float* __restrict__ g1, const float* __restrict__ be1,
                       const float* __restrict__ W2, const float* __restrict__ b2,
                       const float* __restrict__ rel_emb,
                       const float* __restrict__ Wm1, const float* __restrict__ bm1,
                       const float* __restrict__ Wm2, const float* __restrict__ bm2,
                       const float* __restrict__ gn, const float* __restrict__ bn,
                       const float* __restrict__ Wg1, const float* __restrict__ bg1,
                       const float* __restrict__ Wg2, const float* __restrict__ bg2,
                       float* __restrict__ wbuf, u16* __restrict__ frags,
                       const float* __restrict__ te, int* __restrict__ cnt,
                       float* __restrict__ gsum, u32* __restrict__ gmax,
                       int* __restrict__ ticket, int E, int N) {
  int tid = blockIdx.x * 256 + threadIdx.x;
  int nth = gridDim.x * 256;
  if (tid == 0) *ticket = 0;
  for (int i = tid; i < 64; i += nth) {
    wbuf[OB_b1 + i] = b1[i];   wbuf[OB_g1 + i] = g1[i];
    wbuf[OB_be1 + i] = be1[i]; wbuf[OB_b2 + i] = b2[i];
    wbuf[OB_bm1 + i] = bm1[i]; wbuf[OB_w192 + i] = Wm1[192 * 64 + i];
    wbuf[OB_bm2 + i] = bm2[i]; wbuf[OB_gn + i] = gn[i];
    wbuf[OB_bn + i] = bn[i];   wbuf[OB_bg1 + i] = bg1[i];
    wbuf[OB_bg2 + i] = bg2[i];
    gsum[i] = 0.f; gmax[i] = 0u;
  }
  for (int i = tid; i < 8192; i += nth) wbuf[OB_Wg1 + i] = Wg1[i];
  for (int i = tid; i < 4096; i += nth) wbuf[OB_Wg2 + i] = Wg2[i];
  for (int idx = tid; idx < 16384; idx += nth) {
    int f = idx >> 9, L = (idx >> 3) & 63, j = idx & 7;
    int k = (f >> 2) * 32 + ((L >> 4) << 3) + j, n = ((f & 3) << 4) + (L & 15);
    frags[FR_W1 + idx] = f2bf(W1[k * 64 + n]);
  }
  for (int idx = tid; idx < 4096; idx += nth) {
    int f = idx >> 9, L = (idx >> 3) & 63, j = idx & 7;
    int k = (f >> 2) * 32 + ((L >> 4) << 3) + j, n = ((f & 3) << 4) + (L & 15);
    frags[FR_W2 + idx] = f2bf(W2[k * 64 + n]);
  }
  for (int idx = tid; idx < 12288; idx += nth) {
    int f = idx >> 9, L = (idx >> 3) & 63, j = idx & 7;
    int k = (f >> 2) * 32 + ((L >> 4) << 3) + j, n = ((f & 3) << 4) + (L & 15);
    frags[FR_Wm1 + idx] = f2bf(Wm1[k * 64 + n]);
  }
  for (int idx = tid; idx < 4096; idx += nth) {
    int f = idx >> 9, L = (idx >> 3) & 63, j = idx & 7;
    int k = (f >> 2) * 32 + ((L >> 4) << 3) + j, n = ((f & 3) << 4) + (L & 15);
    frags[FR_Wm2 + idx] = f2bf(Wm2[k * 64 + n]);
  }
  for (int idx = tid; idx < 576; idx += nth) {
    int r = idx / 80, c = idx % 80;
    frags[FR_rel + idx] = (r < 7 && c < 64) ? f2bf(rel_emb[r * 64 + c]) : (u16)0;
  }
  // fused dst histogram
  for (int e = tid; e < E; e += nth) {
    float4 v = *(const float4*)(te + (size_t)e * 4);
    int d = min(max((int)v.y, 0), N - 1);
    atomicAdd(&cnt[d], 1);
  }
}

// ---- counting sort by dst: multi-block scan chain ----
#define SCH 512
__launch_bounds__(256)
__global__ void k_scan1(const int* __restrict__ cnt, int* __restrict__ bsum, int N) {
  __shared__ int sd[256];
  int b = blockIdx.x, t = threadIdx.x, base = b * SCH;
  int i0 = base + 2 * t, i1 = i0 + 1;
  int a = 0;
  if (i0 < N) a += cnt[i0];
  if (i1 < N) a += cnt[i1];
  sd[t] = a; __syncthreads();
  for (int s = 128; s > 0; s >>= 1) { if (t < s) sd[t] += sd[t + s]; __syncthreads(); }
  if (t == 0) bsum[b] = sd[0];
}

__launch_bounds__(256)
__global__ void k_scan2(const int* __restrict__ bsum, int* __restrict__ bofs, int NBLK) {
  __shared__ int sd[256];
  int t = threadIdx.x;
  int K = (NBLK + 255) / 256;
  int loc = 0;
  for (int k = 0; k < K; k++) { int i = t * K + k; if (i < NBLK) loc += bsum[i]; }
  sd[t] = loc; __syncthreads();
  for (int s = 1; s < 256; s <<= 1) {
    int o = 0; if (t >= s) o = sd[t - s];
    __syncthreads(); sd[t] += o; __syncthreads();
  }
  int excl = sd[t] - loc;
  int run = excl;
  for (int k = 0; k < K; k++) {
    int i = t * K + k;
    if (i < NBLK) { bofs[i] = run; run += bsum[i]; }
  }
}

__launch_bounds__(256)
__global__ void k_scan3(const int* __restrict__ bofs, int* __restrict__ cur, int N) {
  // cur: counts in, exclusive-prefix cursors out
  __shared__ int sd[256];
  int b = blockIdx.x, t = threadIdx.x, base = b * SCH;
  int i0 = base + 2 * t, i1 = i0 + 1;
  int a0 = (i0 < N) ? cur[i0] : 0, a1 = (i1 < N) ? cur[i1] : 0;
  int pair = a0 + a1;
  sd[t] = pair; __syncthreads();
  for (int s = 1; s < 256; s <<= 1) {
    int o = 0; if (t >= s) o = sd[t - s];
    __syncthreads(); sd[t] += o; __syncthreads();
  }
  int excl = sd[t] - pair + bofs[b];
  if (i0 < N) cur[i0] = excl;
  if (i1 < N) cur[i1] = excl + a0;
}

__launch_bounds__(256)
__global__ void k_place(const float* __restrict__ te, int* __restrict__ cur,
                        uint4* __restrict__ sorted, int E, int N) {
  int i = blockIdx.x * 256 + threadIdx.x, st = gridDim.x * 256;
  for (int e = i; e < E; e += st) {
    float4 v = *(const float4*)(te + (size_t)e * 4);
    int s = min(max((int)v.x, 0), N - 1);
    int d = min(max((int)v.y, 0), N - 1);
    int r = min(max((int)v.z, 0), 6);
    int pos = atomicAdd(&cur[d], 1);
    uint4 rec; rec.x = (u32)s; rec.y = (u32)d; rec.z = (u32)r; rec.w = __float_as_uint(v.w);
    sorted[pos] = rec;
  }
}

// ---- stage A (MFMA): h = relu(relu(LN(X@W1+b1)) @ W2 + b2) ----
__launch_bounds__(256, 4)
__global__ void k_h(const float* __restrict__ X, const float* __restrict__ wbuf,
                    const u16* __restrict__ frags, u16* __restrict__ hb,
                    float* __restrict__ agg, int N) {
  __shared__ __align__(16) float xb[2][16 * 256];   // 2 x 16 KB X tile
  __shared__ __align__(16) u16 st[16 * 72];         // bf16 h1 tile (pad 72)
  __shared__ float sred[2][16][4];                  // row {sum,sumsq} per wave

  int lane = threadIdx.x & 63, wave = threadIdx.x >> 6;
  int m = lane & 15, quad = lane >> 4;
  int col = wave * 16 + m;

  bf16x8 bw1[8], bw2[2];
  #pragma unroll
  for (int ks = 0; ks < 8; ks++)
    bw1[ks] = *(const bf16x8*)(frags + FR_W1 + ((ks * 4 + wave) * 64 + lane) * 8);
  #pragma unroll
  for (int ks = 0; ks < 2; ks++)
    bw2[ks] = *(const bf16x8*)(frags + FR_W2 + ((ks * 4 + wave) * 64 + lane) * 8);

  float b1v = wbuf[OB_b1 + col], g1v = wbuf[OB_g1 + col];
  float be1v = wbuf[OB_be1 + col], b2v = wbuf[OB_b2 + col];

  int ntiles = (N + 15) / 16;
  int xorm = (m & 7) << 4;

  auto stage = [&](int t, int buf) {
    int n0s = t * 16;
    #pragma unroll
    for (int i = 0; i < 4; i++) {
      int r = wave * 4 + i;
      int nr = min(n0s + r, N - 1);
      const char* src = (const char*)(X + (size_t)nr * 256);
      int soff = (lane * 16) ^ ((r & 7) << 4);
      gld_lds16(src + soff, (char*)&xb[buf][0] + r * 1024);
    }
  };

  int cur = 0;
  if (blockIdx.x < ntiles) stage(blockIdx.x, 0);

  for (int t = blockIdx.x; t < ntiles; t += gridDim.x) {
    __syncthreads();
    if (t + (int)gridDim.x < ntiles) stage(t + gridDim.x, cur ^ 1);

    int n0 = t * 16;
    const char* xp = (const char*)&xb[cur][0];

    f32x4 acc = {};
    #pragma unroll
    for (int ks = 0; ks < 8; ks++) {
      int base = m * 1024 + ks * 128 + quad * 32;
      float4 u0 = *(const float4*)(xp + (base ^ xorm));
      float4 u1 = *(const float4*)(xp + ((base + 16) ^ xorm));
      bf16x8 a;
      a[0] = (short)f2bf(u0.x); a[1] = (short)f2bf(u0.y);
      a[2] = (short)f2bf(u0.z); a[3] = (short)f2bf(u0.w);
      a[4] = (short)f2bf(u1.x); a[5] = (short)f2bf(u1.y);
      a[6] = (short)f2bf(u1.z); a[7] = (short)f2bf(u1.w);
      acc = MFMA(a, bw1[ks], acc);
    }

    float vv[4];
    #pragma unroll
    for (int r = 0; r < 4; r++) vv[r] = acc[r] + b1v;
    #pragma unroll
    for (int r = 0; r < 4; r++) {
      float s = vv[r], q = vv[r] * vv[r];
      #pragma unroll
      for (int mk = 8; mk >= 1; mk >>= 1) {
        s += __shfl_xor(s, mk, 64);
        q += __shfl_xor(q, mk, 64);
      }
      if (m == 0) { sred[0][quad * 4 + r][wave] = s; sred[1][quad * 4 + r][wave] = q; }
    }
    __syncthreads();
    #pragma unroll
    for (int r = 0; r < 4; r++) {
      int row = quad * 4 + r;
      float4 S = *(const float4*)&sred[0][row][0];
      float4 Q = *(const float4*)&sred[1][row][0];
      float mu = (S.x + S.y + S.z + S.w) * (1.f / 64.f);
      float vq = (Q.x + Q.y + Q.z + Q.w) * (1.f / 64.f) - mu * mu;
      float rs = rsqrtf(fmaxf(vq, 0.f) + EPS);
      float h1 = fmaxf(fmaf((vv[r] - mu) * rs, g1v, be1v), 0.f);
      st[row * 72 + col] = f2bf(h1);
    }
    __syncthreads();

    f32x4 acc2 = {};
    #pragma unroll
    for (int ks = 0; ks < 2; ks++) {
      bf16x8 a2 = *(const bf16x8*)(st + m * 72 + ks * 32 + quad * 8);
      acc2 = MFMA(a2, bw2[ks], acc2);
    }
    #pragma unroll
    for (int r = 0; r < 4; r++) {
      int row = n0 + quad * 4 + r;
      if (row < N) {
        float hv = fmaxf(acc2[r] + b2v, 0.f);
        hb[(size_t)row * 64 + col] = f2bf(hv);
        agg[(size_t)row * 64 + col] = hv;
      }
    }
    cur ^= 1;
  }
}

// ---- stage B+C (MFMA): edge MLP, gather-pipelined, LDS-tile run-reduction ----
__launch_bounds__(512, 4)
__global__ void k_edge(const uint4* __restrict__ sorted, const u16* __restrict__ hb,
                       const float* __restrict__ wbuf, const u16* __restrict__ frags,
                       float* __restrict__ agg, int E, int N) {
  __shared__ __align__(16) u16 sWm1[24 * 512];
  __shared__ __align__(16) u16 sWm2[8 * 512];
  __shared__ __align__(16) u16 srel[576];
  __shared__ __align__(16) float st32[8][16 * 68];  // per-wave f32 tile (t, then out)
  __shared__ int sdst[8][16];

  {
    const uint4* s1 = (const uint4*)(frags + FR_Wm1);
    uint4* d1 = (uint4*)sWm1;
    for (int i = threadIdx.x; i < 1536; i += 512) d1[i] = s1[i];
    const uint4* s2 = (const uint4*)(frags + FR_Wm2);
    uint4* d2 = (uint4*)sWm2;
    for (int i = threadIdx.x; i < 512; i += 512) d2[i] = s2[i];
    const uint4* s3 = (const uint4*)(frags + FR_rel);
    uint4* d3 = (uint4*)srel;
    for (int i = threadIdx.x; i < 72; i += 512) d3[i] = s3[i];
  }
  __syncthreads();

  int lane = threadIdx.x & 63, wave = threadIdx.x >> 6;
  int m = lane & 15, quad = lane >> 4, koff = quad * 8, col0 = m;
  float* st = st32[wave];
  int* dstS = sdst[wave];

  float bm1v[4], w192v[4], bm2v[4];
  #pragma unroll
  for (int nt = 0; nt < 4; nt++) {
    int c = nt * 16 + col0;
    bm1v[nt] = wbuf[OB_bm1 + c];
    w192v[nt] = wbuf[OB_w192 + c];
    bm2v[nt] = wbuf[OB_bm2 + c];
  }

  int ntiles = (E + 15) >> 4;
  int gw = blockIdx.x * 8 + wave, nwv = gridDim.x * 8;
  int per = (ntiles + nwv - 1) / nwv;
  int tile = gw * per, tend = min(tile + per, ntiles);

  int cd = -1; float cv = 0.f;  // per-lane run carry (lane owns column `lane`)
  int dstv = -1; float wv = 0.f;
  bf16x8 af[6];

  if (tile < tend) {  // prologue: rec + gathers for first tile
    int srcv = 0, relv = 0;
    if (lane < 16) {
      int e = tile * 16 + lane;
      uint4 rc = sorted[min(e, E - 1)];
      srcv = (int)rc.x; dstv = (e < E) ? (int)rc.y : -1;
      relv = (int)rc.z; wv = __uint_as_float(rc.w);
    }
    int sm = __shfl(srcv, m, 64), dmv = __shfl(dstv, m, 64), rm = __shfl(relv, m, 64);
    int dmg = dmv < 0 ? 0 : dmv;
    const u16* hs = hb + (size_t)sm * 64;
    const u16* hd = hb + (size_t)dmg * 64;
    af[0] = *(const bf16x8*)(hs + koff);
    af[1] = *(const bf16x8*)(hs + 32 + koff);
    af[2] = *(const bf16x8*)(hd + koff);
    af[3] = *(const bf16x8*)(hd + 32 + koff);
    af[4] = *(const bf16x8*)(srel + rm * 80 + koff);
    af[5] = *(const bf16x8*)(srel + rm * 80 + 32 + koff);
  }

  for (; tile < tend; tile++) {
    bool hasnext = (tile + 1) < tend;

    // current tile's dst codes -> LDS (consumed by the run-reduce below)
    if (lane < 16) dstS[lane] = dstv;

    // prefetch next sorted rec (MFMA1 covers its latency)
    int srcn = 0, dstn = -1, reln = 0; float wn = 0.f;
    if (hasnext && lane < 16) {
      int e = (tile + 1) * 16 + lane;
      uint4 rc = sorted[min(e, E - 1)];
      srcn = (int)rc.x; dstn = (e < E) ? (int)rc.y : -1;
      reln = (int)rc.z; wn = __uint_as_float(rc.w);
    }

    // ---- MFMA1 on current tile ----
    f32x4 acc[4] = {};
    #pragma unroll
    for (int ks = 0; ks < 6; ks++)
      #pragma unroll
      for (int nt = 0; nt < 4; nt++) {
        bf16x8 b = *(const bf16x8*)(sWm1 + (ks * 4 + nt) * 512 + lane * 8);
        acc[nt] = MFMA(af[ks], b, acc[nt]);
      }

    // ---- issue next tile's gathers (af regs free now) ----
    if (hasnext) {
      int sm = __shfl(srcn, m, 64), dmv = __shfl(dstn, m, 64), rm = __shfl(reln, m, 64);
      int dmg = dmv < 0 ? 0 : dmv;
      const u16* hs = hb + (size_t)sm * 64;
      const u16* hd = hb + (size_t)dmg * 64;
      af[0] = *(const bf16x8*)(hs + koff);
      af[1] = *(const bf16x8*)(hs + 32 + koff);
      af[2] = *(const bf16x8*)(hd + koff);
      af[3] = *(const bf16x8*)(hd + 32 + koff);
      af[4] = *(const bf16x8*)(srel + rm * 80 + koff);
      af[5] = *(const bf16x8*)(srel + rm * 80 + 32 + koff);
    }

    // ---- epilogue 1: + bm1 + w*Wm1[192], relu -> f32 LDS tile (t) ----
    float wrow[4];
    #pragma unroll
    for (int r = 0; r < 4; r++) wrow[r] = __shfl(wv, quad * 4 + r, 64);
    #pragma unroll
    for (int nt = 0; nt < 4; nt++)
      #pragma unroll
      for (int r = 0; r < 4; r++) {
        float v = fmaf(wrow[r], w192v[nt], acc[nt][r] + bm1v[nt]);
        st[(quad * 4 + r) * 68 + nt * 16 + col0] = fmaxf(v, 0.f);
      }
    __builtin_amdgcn_wave_barrier();

    f32x4 acc2[4] = {};
    #pragma unroll
    for (int ks = 0; ks < 2; ks++) {
      float4 p0 = *(const float4*)(st + m * 68 + ks * 32 + koff);
      float4 p1 = *(const float4*)(st + m * 68 + ks * 32 + koff + 4);
      bf16x8 a2;
      a2[0] = (short)f2bf(p0.x); a2[1] = (short)f2bf(p0.y);
      a2[2] = (short)f2bf(p0.z); a2[3] = (short)f2bf(p0.w);
      a2[4] = (short)f2bf(p1.x); a2[5] = (short)f2bf(p1.y);
      a2[6] = (short)f2bf(p1.z); a2[7] = (short)f2bf(p1.w);
      #pragma unroll
      for (int nt = 0; nt < 4; nt++) {
        bf16x8 b = *(const bf16x8*)(sWm2 + (ks * 4 + nt) * 512 + lane * 8);
        acc2[nt] = MFMA(a2, b, acc2[nt]);
      }
    }
    __builtin_amdgcn_wave_barrier();

    // overwrite the f32 tile with the output messages (+bm2)
    #pragma unroll
    for (int nt = 0; nt < 4; nt++)
      #pragma unroll
      for (int r = 0; r < 4; r++)
        st[(quad * 4 + r) * 68 + nt * 16 + col0] = acc2[nt][r] + bm2v[nt];
    __builtin_amdgcn_wave_barrier();

    // columnar segmented run-reduction; one coalesced atomic per run boundary
    #pragma unroll
    for (int r = 0; r < 16; r++) {
      int d = dstS[r];
      float v = st[r * 68 + lane];
      if (d != cd) {
        if (cd >= 0) atomicAdd(agg + (size_t)cd * 64 + lane, cv);
        cd = d; cv = 0.f;
      }
      if (d >= 0) cv += v;
    }
    __builtin_amdgcn_wave_barrier();

    dstv = dstn; wv = wn;
  }
  if (cd >= 0) atomicAdd(agg + (size_t)cd * 64 + lane, cv);
}

// ---- stage D1+D2 fused: LN(agg) column sum/max; last block runs final MLP ----
// Grid kept SMALL (384): gsum/gmax same-line atomic RMWs scale with block
// count — 2048 blocks serialized ~68 us on 4 cache lines (round-9 counters).
__launch_bounds__(256)
__global__ void k_nodes(const float* __restrict__ agg, const float* __restrict__ wbuf,
                        float* __restrict__ gsum, u32* __restrict__ gmax,
                        int* __restrict__ ticket, float* __restrict__ out, int N) {
  int lane = threadIdx.x & 63, wave = threadIdx.x >> 6;
  int r4 = lane >> 4, c4 = (lane & 15) * 4;
  float4 gnv = *(const float4*)(wbuf + OB_gn + c4);
  float4 bnv = *(const float4*)(wbuf + OB_bn + c4);
  int wid = blockIdx.x * 4 + wave, nw = gridDim.x * 4;
  float sj[4] = {0.f, 0.f, 0.f, 0.f};
  float mj[4] = {-3.0e38f, -3.0e38f, -3.0e38f, -3.0e38f};
  for (int base = wid * 4; base < N; base += nw * 4) {
    int row = base + r4;
    bool ok = row < N;
    float4 av = ok ? *(const float4*)(agg + (size_t)row * 64 + c4)
                   : make_float4(0.f, 0.f, 0.f, 0.f);
    float s = av.x + av.y + av.z + av.w;
    #pragma unroll
    for (int mk = 8; mk >= 1; mk >>= 1) s += __shfl_xor(s, mk, 64);
    float mu = s * (1.f / 64.f);
    float d0 = av.x - mu, d1 = av.y - mu, d2 = av.z - mu, d3 = av.w - mu;
    float q = d0 * d0 + d1 * d1 + d2 * d2 + d3 * d3;
    #pragma unroll
    for (int mk = 8; mk >= 1; mk >>= 1) q += __shfl_xor(q, mk, 64);
    float rs = rsqrtf(q * (1.f / 64.f) + EPS);
    if (ok) {
      float t0 = fmaf(d0 * rs, gnv.x, bnv.x);
      float t1 = fmaf(d1 * rs, gnv.y, bnv.y);
      float t2 = fmaf(d2 * rs, gnv.z, bnv.z);
      float t3 = fmaf(d3 * rs, gnv.w, bnv.w);
      sj[0] += t0; mj[0] = fmaxf(mj[0], t0);
      sj[1] += t1; mj[1] = fmaxf(mj[1], t1);
      sj[2] += t2; mj[2] = fmaxf(mj[2], t2);
      sj[3] += t3; mj[3] = fmaxf(mj[3], t3);
    }
  }
  #pragma unroll
  for (int j = 0; j < 4; j++) {
    sj[j] += __shfl_xor(sj[j], 16, 64);
    sj[j] += __shfl_xor(sj[j], 32, 64);
    mj[j] = fmaxf(mj[j], __shfl_xor(mj[j], 16, 64));
    mj[j] = fmaxf(mj[j], __shfl_xor(mj[j], 32, 64));
  }
  __shared__ float bs[4][64], bm[4][64];
  if (lane < 16) {
    #pragma unroll
    for (int j = 0; j < 4; j++) { bs[wave][c4 + j] = sj[j]; bm[wave][c4 + j] = mj[j]; }
  }
  __syncthreads();
  if (threadIdx.x < 64) {
    int c = threadIdx.x;
    float ts = bs[0][c] + bs[1][c] + bs[2][c] + bs[3][c];
    float tm = fmaxf(fmaxf(bm[0][c], bm[1][c]), fmaxf(bm[2][c], bm[3][c]));
    atomicAdd(gsum + c, ts);
    atomicMax(gmax + c, fkey(tm));
  }
  __syncthreads();

  __shared__ int slast;
  if (threadIdx.x == 0) {
    __threadfence();
    slast = atomicAdd(ticket, 1);
  }
  __syncthreads();
  if (slast == (int)gridDim.x - 1) {   // last block: final 2-layer MLP
    __threadfence();
    __shared__ float g[128];
    __shared__ float y1[64];
    int t = threadIdx.x;
    if (t < 64) {
      g[t] = atomicAdd(gsum + t, 0.f) / (float)N;   // atomic read (coherent)
    } else if (t < 128) {
      u32 k = atomicOr(gmax + (t - 64), 0u);
      u32 b = (k & 0x80000000u) ? (k & 0x7fffffffu) : ~k;
      g[t] = __uint_as_float(b);
    }
    __syncthreads();
    if (t < 64) {
      float a = wbuf[OB_bg1 + t];
      for (int i = 0; i < 128; i++) a = fmaf(g[i], wbuf[OB_Wg1 + i * 64 + t], a);
      y1[t] = fmaxf(a, 0.f);
    }
    __syncthreads();
    if (t < 64) {
      float a = wbuf[OB_bg2 + t];
      for (int k = 0; k < 64; k++) a = fmaf(y1[k], wbuf[OB_Wg2 + k * 64 + t], a);
      out[t] = a;
    }
  }
}

extern "C" void kernel_launch(void* const* d_in, const int* in_sizes, int n_in,
                              void* d_out, int out_size, void* d_ws, size_t ws_size,
                              hipStream_t stream) {
  const int N = in_sizes[0] / 256;
  const int E = in_sizes[1] / 4;
  const int NBLK = (N + SCH - 1) / SCH;

  char* ws = (char*)d_ws;
  size_t p = 0;
  auto rup = [](size_t x) { return (x + 255) & ~(size_t)255; };
  uint4* sorted = (uint4*)(ws + p); p += rup((size_t)E * 16);
  float* agg    = (float*)(ws + p); p += rup((size_t)N * 64 * 4);
  u16*   hb     = (u16*)(ws + p);   p += rup((size_t)N * 128);
  int*   cur    = (int*)(ws + p);   p += rup((size_t)N * 4);
  int*   bsum   = (int*)(ws + p);   p += rup((size_t)(NBLK + 1) * 4);
  int*   bofs   = (int*)(ws + p);   p += rup((size_t)(NBLK + 1) * 4);
  float* gsum   = (float*)(ws + p); p += 256;
  u32*   gmax   = (u32*)(ws + p);   p += 256;
  int*   ticket = (int*)(ws + p);   p += 256;
  float* wbuf   = (float*)(ws + p); p += rup((size_t)WB_TOT * 4);
  u16*   frags  = (u16*)(ws + p);   p += rup((size_t)FR_TOT * 2);

  const float* X  = (const float*)d_in[0];
  const float* te = (const float*)d_in[1];

  hipMemsetAsync(cur, 0, (size_t)N * 4, stream);
  hipLaunchKernelGGL(k_prep, dim3(1024), dim3(256), 0, stream,
                     (const float*)d_in[2], (const float*)d_in[3], (const float*)d_in[4],
                     (const float*)d_in[5], (const float*)d_in[6], (const float*)d_in[7],
                     (const float*)d_in[8], (const float*)d_in[9], (const float*)d_in[10],
                     (const float*)d_in[11], (const float*)d_in[12], (const float*)d_in[13],
                     (const float*)d_in[14], (const float*)d_in[15], (const float*)d_in[16],
                     (const float*)d_in[17], (const float*)d_in[18], wbuf, frags,
                     te, cur, gsum, gmax, ticket, E, N);

  hipLaunchKernelGGL(k_scan1, dim3(NBLK), dim3(256), 0, stream, cur, bsum, N);
  hipLaunchKernelGGL(k_scan2, dim3(1), dim3(256), 0, stream, bsum, bofs, NBLK);
  hipLaunchKernelGGL(k_scan3, dim3(NBLK), dim3(256), 0, stream, bofs, cur, N);
  hipLaunchKernelGGL(k_place, dim3(1024), dim3(256), 0, stream, te, cur, sorted, E, N);

  hipLaunchKernelGGL(k_h, dim3(1024), dim3(256), 0, stream, X, wbuf, frags, hb, agg, N);
  hipLaunchKernelGGL(k_edge, dim3(512), dim3(512), 0, stream, sorted, hb, wbuf, frags, agg, E, N);
  hipLaunchKernelGGL(k_nodes, dim3(384), dim3(256), 0, stream, agg, wbuf, gsum, gmax,
                     ticket, (float*)d_out, N);
}